// Round 11
// baseline (499.691 us; speedup 1.0000x reference)
//
#include <hip/hip_runtime.h>

typedef unsigned short u16;
typedef unsigned short ushort8 __attribute__((ext_vector_type(8)));
typedef unsigned short us4 __attribute__((ext_vector_type(4)));
typedef __bf16 bf16x8 __attribute__((ext_vector_type(8)));
typedef float f32x4 __attribute__((ext_vector_type(4)));

#define DEV static __device__ __forceinline__

// ---------- helpers ----------
DEV u16 f2bf(float f) {   // round-to-nearest-even f32 -> bf16
    unsigned int u = __builtin_bit_cast(unsigned int, f);
    u += 0x7FFFu + ((u >> 16) & 1u);
    return (u16)(u >> 16);
}

DEV f32x4 mfma16(ushort8 a, ushort8 b, f32x4 c) {
    return __builtin_amdgcn_mfma_f32_16x16x32_bf16((bf16x8)a, (bf16x8)b, c, 0, 0, 0);
}

DEV void gload_lds16(const void* g, void* l) {   // async global->LDS, dst = base + lane*16
    __builtin_amdgcn_global_load_lds(
        (const __attribute__((address_space(1))) void*)g,
        (__attribute__((address_space(3))) void*)l, 16, 0, 0);
}

// ---------- fused prep: x cvt + Wq/Wk/Wv transpose + Wu transpose (one launch) ----------
__global__ void prep_kernel(const float* __restrict__ x,
                            const float* __restrict__ Wq, const float* __restrict__ Wk,
                            const float* __restrict__ Wv, const float* __restrict__ Wu,
                            u16* __restrict__ xb, u16* __restrict__ Wqt, u16* __restrict__ Wut) {
    __shared__ u16 tile[64][72];
    const int bid = blockIdx.x;

    if (bid < 2048) {                              // x fp32 -> bf16, vectorized
        int i = (bid * 256 + threadIdx.x) * 4;
        float4 f = *(const float4*)(x + i);
        us4 o;
        o.x = f2bf(f.x); o.y = f2bf(f.y); o.z = f2bf(f.z); o.w = f2bf(f.w);
        *(us4*)(xb + i) = o;
        return;
    }

    const float* in;
    u16* out;
    int R, C, c0, r0;
    if (bid < 3584) {                              // Wq/Wk/Wv [512][4096] -> ^T bf16
        int j = bid - 2048;
        int z = j >> 9, rem = j & 511;
        in = (z == 0) ? Wq : (z == 1) ? Wk : Wv;
        out = Wqt + (size_t)z * 2097152;           // 4 MB stride
        R = 512; C = 4096;
        c0 = (rem & 63) << 6; r0 = (rem >> 6) << 6;
    } else {                                       // Wu [4096][512] -> ^T bf16
        int k = bid - 3584;
        in = Wu; out = Wut;
        R = 4096; C = 512;
        c0 = (k & 7) << 6; r0 = (k >> 3) << 6;
    }
    int tx = threadIdx.x & 63, ty = threadIdx.x >> 6;
    for (int i = 0; i < 64; i += 4) {
        int r = i + ty;
        tile[r][tx] = f2bf(in[(size_t)(r0 + r) * C + c0 + tx]);
    }
    __syncthreads();
    for (int i = 0; i < 64; i += 4) {
        int r = i + ty;
        out[(size_t)(c0 + r) * R + r0 + tx] = tile[tx][r];
    }
}

// ---------- QKV GEMM (z-fused): C = xb @ W{q,k,v}t^T, 128x128 tile, Kc=512 ----------
// z==2 (V) stores directly transposed to Vtb [bh][d][t] (packed 8B, kills transpose).
__launch_bounds__(256, 3)
__global__ void gemm_qkv(const u16* __restrict__ A, const u16* __restrict__ Btbase,
                         float s2, u16* __restrict__ outbase, u16* __restrict__ vtb) {
    __shared__ u16 Asub[128 * 32];
    __shared__ u16 Bsub[128 * 32];
    const int Kc = 512;
    const u16* Bt = Btbase + (size_t)blockIdx.z * 2097152;     // 4 MB stride
    u16* out = outbase + (size_t)blockIdx.z * 16777216;        // 32 MB stride (z=0,1)
    const float scale = (blockIdx.z == 0) ? s2 : 1.0f;

    const int tid = threadIdx.x, lane = tid & 63, wv = tid >> 6;
    const int bm = blockIdx.y << 7, bn = blockIdx.x << 7;
    const int wr = (wv >> 1) << 6, wc = (wv & 1) << 6;
    const int lr = lane & 15, hi = lane >> 4;

    f32x4 acc[4][4] = {};

    int off0 = (wv * 2048 + lane * 16) >> 1;
    int row0 = off0 >> 5, k0e = off0 & 31;
    int off1 = off0 + 512;
    int row1 = off1 >> 5, k1e = off1 & 31;

    const u16* Ag0 = A + (size_t)(bm + row0) * Kc + k0e;
    const u16* Ag1 = A + (size_t)(bm + row1) * Kc + k1e;
    const u16* Bg0 = Bt + (size_t)(bn + row0) * Kc + k0e;
    const u16* Bg1 = Bt + (size_t)(bn + row1) * Kc + k1e;

    for (int kk = 0; kk < Kc; kk += 32) {
        __syncthreads();
        gload_lds16(Ag0 + kk, &Asub[wv * 1024]);
        gload_lds16(Ag1 + kk, &Asub[wv * 1024 + 512]);
        gload_lds16(Bg0 + kk, &Bsub[wv * 1024]);
        gload_lds16(Bg1 + kk, &Bsub[wv * 1024 + 512]);
        __syncthreads();

        ushort8 a[4], b[4];
#pragma unroll
        for (int m = 0; m < 4; ++m)
            a[m] = *(const ushort8*)&Asub[(wr + m * 16 + lr) * 32 + hi * 8];
#pragma unroll
        for (int n = 0; n < 4; ++n)
            b[n] = *(const ushort8*)&Bsub[(wc + n * 16 + lr) * 32 + hi * 8];
#pragma unroll
        for (int m = 0; m < 4; ++m)
#pragma unroll
            for (int n = 0; n < 4; ++n)
                acc[m][n] = mfma16(a[m], b[n], acc[m][n]);
    }

    if (blockIdx.z == 2) {
#pragma unroll
        for (int m = 0; m < 4; ++m)
#pragma unroll
            for (int n = 0; n < 4; ++n) {
                int row0v = bm + wr + m * 16 + hi * 4;     // token = b*2048 + t0 (t0 % 4 == 0)
                int col   = bn + wc + n * 16 + lr;         // h*512 + d
                int b = row0v >> 11, t0 = row0v & 2047;
                int h = col >> 9, d = col & 511;
                us4 pk;
#pragma unroll
                for (int r = 0; r < 4; ++r) pk[r] = f2bf(acc[m][n][r]);
                *(us4*)&vtb[(((size_t)(b * 8 + h) * 512 + d) << 11) + t0] = pk;
            }
    } else {
#pragma unroll
        for (int m = 0; m < 4; ++m)
#pragma unroll
            for (int n = 0; n < 4; ++n)
#pragma unroll
                for (int r = 0; r < 4; ++r) {
                    int row = bm + wr + m * 16 + hi * 4 + r;
                    int col = bn + wc + n * 16 + lr;
                    float v = acc[m][n][r] * scale;
                    size_t dst = ((size_t)((row >> 11) * 8 + (col >> 9)) * 2048 + (row & 2047)) * 512
                                 + (col & 511);
                    out[dst] = f2bf(v);
                }
    }
}

// ---------- final GEMM: out[4096][512] = Ob[4096][4096] @ Wut[512][4096]^T + bu ----------
__launch_bounds__(256, 3)
__global__ void gemm_final(const u16* __restrict__ A, const u16* __restrict__ Bt,
                           const float* __restrict__ bias, float* __restrict__ out, int Kc) {
    __shared__ u16 Asub[128 * 32];
    __shared__ u16 Bsub[64 * 32];
    const int tid = threadIdx.x, lane = tid & 63, wv = tid >> 6;
    const int bm = blockIdx.y << 7, bn = blockIdx.x << 6;
    const int wr = (wv >> 1) << 6, wc = (wv & 1) << 5;
    const int lr = lane & 15, hi = lane >> 4;

    f32x4 acc[4][2] = {};

    const u16* gsrc[3];
    u16* ldst[3];
#pragma unroll
    for (int j = 0; j < 3; ++j) {
        int g = wv * 3 + j;
        int off = g * 512 + lane * 8;
        if (g < 8) {
            int row = off >> 5, k = off & 31;
            gsrc[j] = A + (size_t)(bm + row) * Kc + k;
            ldst[j] = &Asub[g * 512];
        } else {
            int off2 = off - 4096;
            int row = off2 >> 5, k = off2 & 31;
            gsrc[j] = Bt + (size_t)(bn + row) * Kc + k;
            ldst[j] = &Bsub[(g - 8) * 512];
        }
    }

    for (int kk = 0; kk < Kc; kk += 32) {
        __syncthreads();
#pragma unroll
        for (int j = 0; j < 3; ++j) gload_lds16(gsrc[j] + kk, ldst[j]);
        __syncthreads();

        ushort8 a[4], b[2];
#pragma unroll
        for (int m = 0; m < 4; ++m)
            a[m] = *(const ushort8*)&Asub[(wr + m * 16 + lr) * 32 + hi * 8];
#pragma unroll
        for (int n = 0; n < 2; ++n)
            b[n] = *(const ushort8*)&Bsub[(wc + n * 16 + lr) * 32 + hi * 8];
#pragma unroll
        for (int m = 0; m < 4; ++m)
#pragma unroll
            for (int n = 0; n < 2; ++n)
                acc[m][n] = mfma16(a[m], b[n], acc[m][n]);
    }

#pragma unroll
    for (int m = 0; m < 4; ++m)
#pragma unroll
        for (int n = 0; n < 2; ++n)
#pragma unroll
            for (int r = 0; r < 4; ++r) {
                int row = bm + wr + m * 16 + hi * 4 + r;
                int col = bn + wc + n * 16 + lr;
                out[(size_t)row * 512 + col] = acc[m][n][r] + bias[col];
            }
}

// ---------- flash attention v11: dual-stream fused phase ----------
// iter t: softmax(t-1) [VALU, exposed] -> barrier -> prefetch K(t+2) ->
//         { S(t) ds_read+MFMA  INTERLEAVED  PV(t-1) V-load+reg-MFMA }.
// The two MFMA streams are independent: PV's reg-only MFMAs cover S's ds_read
// latency; S's MFMAs cover PV's V-load latency. Replaces T15's softmax-in-shadow
// (softmax now exposed, but the merged region removes both phases' latency ramps).
// Buffer protocol: DMA(t+1) issues post-barrier(t) (prior readers of that buf are
// behind barrier(t)); drained by barrier(t+1)'s vmcnt(0). P slot (t-1)&1: read in
// fused(t), next written by softmax(t+1) pre-barrier(t+2) — spans barrier(t+1).
__launch_bounds__(512, 2)
__global__ void attn_kernel(const u16* __restrict__ Q, const u16* __restrict__ K,
                            const u16* __restrict__ Vt, u16* __restrict__ O) {
    __shared__ u16 Klds[2][32 * 512];            // 2 x 32KB, XOR-swizzled rows
    __shared__ u16 Plds[2][128 * 40];            // [q][32 keys + 8 pad]
    __shared__ __align__(16) float red[2][128];  // per-row alpha
    __shared__ __align__(16) float lred[128];    // final l
    __shared__ int rflag[2][8];                  // per-wave "some row rescaled"

    const int tid = threadIdx.x, lane = tid & 63, wv = tid >> 6;
    const int lr = lane & 15, hi = lane >> 4;
    const int qh = wv >> 2, ds = wv & 3;         // PV decomposition

    // XCD-chunked bijective swizzle: 256 blocks = 8 XCDs x 32; 2 bh per XCD chunk
    const int flat = blockIdx.x;
    const int nid = (flat & 7) * 32 + (flat >> 3);
    const int bh = nid >> 4;
    const int q0 = (nid & 15) << 7;

    // Q fragments (B-operand: col=lane&15 -> q-row wv*16+lr, k-slice hi*8..+8)
    ushort8 qf[16];
    {
        const char* Qg = (const char*)(Q + ((size_t)bh * 2048 + q0 + wv * 16 + lr) * 512) + hi * 16;
#pragma unroll
        for (int ks = 0; ks < 16; ++ks) qf[ks] = *(const ushort8*)(Qg + ks * 64);
    }

    f32x4 acc[4][8] = {};   // [q 16-block within 64-row half][d 16-frag within 128-wide slice]
    float mrun = -1e30f, lrun = 0.f;   // per-lane, q = wv*16+lr (replicated over hi), base-2
    f32x4 s0c, s1c;                    // live S results (consumed by next iter's softmax)

    const char* Kg = (const char*)(K + (size_t)bh * 2048 * 512);
    const char* Vg = (const char*)(Vt + (size_t)bh * 512 * 2048);

    auto prefetch_k = [&](int tt) {   // stage K(tt) into buf tt&1
        const char* Kgt = Kg + (size_t)tt * 32 * 1024;
#pragma unroll
        for (int r4 = 0; r4 < 4; ++r4) {
            int r = wv * 4 + r4;
            gload_lds16(Kgt + (size_t)r * 1024 + ((lane ^ (r & 7)) << 4),
                        &Klds[tt & 1][(size_t)r * 512]);
        }
    };

    // S-only phase (prologue tile 0)
    auto s_phase = [&](const char* Kb) {
        s0c = (f32x4){0.f, 0.f, 0.f, 0.f};
        s1c = (f32x4){0.f, 0.f, 0.f, 0.f};
#pragma unroll
        for (int ks = 0; ks < 16; ++ks) {
            int swz = (ks * 64 + hi * 16) ^ ((lr & 7) << 4);
            ushort8 kf0 = *(const ushort8*)(Kb + lr * 1024 + swz);
            ushort8 kf1 = *(const ushort8*)(Kb + (lr + 16) * 1024 + swz);
            s0c = mfma16(kf0, qf[ks], s0c);
            s1c = mfma16(kf1, qf[ks], s1c);
        }
    };

    // softmax on the live S pair; writes P/alpha/flag into slot pcb
    auto softmax_store = [&](int pcb) {
        float mx = fmaxf(fmaxf(fmaxf(s0c[0], s0c[1]), fmaxf(s0c[2], s0c[3])),
                         fmaxf(fmaxf(s1c[0], s1c[1]), fmaxf(s1c[2], s1c[3])));
        mx = fmaxf(mx, __shfl_xor(mx, 16));
        mx = fmaxf(mx, __shfl_xor(mx, 32));
        float a = 1.0f;
        bool upd = false;
        if (mx > mrun + 11.5f) { a = exp2f(mrun - mx); mrun = mx; upd = true; }   // defer-max
        float p[8];
#pragma unroll
        for (int r = 0; r < 4; ++r) {
            p[r]     = exp2f(s0c[r] - mrun);
            p[4 + r] = exp2f(s1c[r] - mrun);
        }
        float ps = ((p[0] + p[1]) + (p[2] + p[3])) + ((p[4] + p[5]) + (p[6] + p[7]));
        ps += __shfl_xor(ps, 16);
        ps += __shfl_xor(ps, 32);
        lrun = lrun * a + ps;

        const int qr = wv * 16 + lr;
        char* Pb = (char*)&Plds[pcb][0] + qr * 80;
        uint2 w01, w23;
        w01.x = (unsigned)f2bf(p[0]) | ((unsigned)f2bf(p[1]) << 16);
        w01.y = (unsigned)f2bf(p[2]) | ((unsigned)f2bf(p[3]) << 16);
        w23.x = (unsigned)f2bf(p[4]) | ((unsigned)f2bf(p[5]) << 16);
        w23.y = (unsigned)f2bf(p[6]) | ((unsigned)f2bf(p[7]) << 16);
        *(uint2*)(Pb + hi * 8) = w01;
        *(uint2*)(Pb + 32 + hi * 8) = w23;
        if (hi == 0) red[pcb][qr] = a;
        if (lane == 0) rflag[pcb][wv] = __any(upd) ? 1 : 0;
    };

    // rescale (defer-max gated); then S(t) and PV(t-1) interleaved 2:1 per ks-pair
    auto fused_phase = [&](int t, int pcb, int ktv) {
        int anyupd = rflag[pcb][0] | rflag[pcb][1] | rflag[pcb][2] | rflag[pcb][3]
                   | rflag[pcb][4] | rflag[pcb][5] | rflag[pcb][6] | rflag[pcb][7];
        if (anyupd) {
#pragma unroll
            for (int mf = 0; mf < 4; ++mf) {
                f32x4 a4 = *(const f32x4*)&red[pcb][qh * 64 + mf * 16 + hi * 4];
#pragma unroll
                for (int nf = 0; nf < 8; ++nf)
#pragma unroll
                    for (int r = 0; r < 4; ++r) acc[mf][nf][r] *= a4[r];
            }
        }
        ushort8 pf[4];
#pragma unroll
        for (int mf = 0; mf < 4; ++mf)
            pf[mf] = *(const ushort8*)((const char*)&Plds[pcb][0]
                                       + (qh * 64 + mf * 16 + lr) * 80 + hi * 16);
        const char* Kb = (const char*)&Klds[t & 1][0];
        s0c = (f32x4){0.f, 0.f, 0.f, 0.f};
        s1c = (f32x4){0.f, 0.f, 0.f, 0.f};
        ushort8 vf;
        __builtin_amdgcn_s_setprio(1);
#pragma unroll
        for (int ks = 0; ks < 16; ++ks) {
            int swz = (ks * 64 + hi * 16) ^ ((lr & 7) << 4);
            ushort8 kf0 = *(const ushort8*)(Kb + lr * 1024 + swz);
            ushort8 kf1 = *(const ushort8*)(Kb + (lr + 16) * 1024 + swz);
            if ((ks & 1) == 0) {          // load V frag one pair ahead of its use
                int nf = ks >> 1;
                int d = ds * 128 + nf * 16 + lr;
                vf = *(const ushort8*)(Vg + (size_t)d * 4096 + (size_t)ktv * 2 + hi * 16);
            }
            s0c = mfma16(kf0, qf[ks], s0c);
            s1c = mfma16(kf1, qf[ks], s1c);
            if (ks & 1) {                 // 4 reg-only PV MFMAs cover next ds_reads
                int nf = ks >> 1;
#pragma unroll
                for (int mf = 0; mf < 4; ++mf) acc[mf][nf] = mfma16(pf[mf], vf, acc[mf][nf]);
            }
        }
        __builtin_amdgcn_s_setprio(0);
    };

    // PV-only (epilogue tile 63)
    auto pv_phase = [&](int pcb, int ktv) {
        int anyupd = rflag[pcb][0] | rflag[pcb][1] | rflag[pcb][2] | rflag[pcb][3]
                   | rflag[pcb][4] | rflag[pcb][5] | rflag[pcb][6] | rflag[pcb][7];
        if (anyupd) {
#pragma unroll
            for (int mf = 0; mf < 4; ++mf) {
                f32x4 a4 = *(const f32x4*)&red[pcb][qh * 64 + mf * 16 + hi * 4];
#pragma unroll
                for (int nf = 0; nf < 8; ++nf)
#pragma unroll
                    for (int r = 0; r < 4; ++r) acc[mf][nf][r] *= a4[r];
            }
        }
        ushort8 pf[4];
#pragma unroll
        for (int mf = 0; mf < 4; ++mf)
            pf[mf] = *(const ushort8*)((const char*)&Plds[pcb][0]
                                       + (qh * 64 + mf * 16 + lr) * 80 + hi * 16);
#pragma unroll
        for (int nf = 0; nf < 8; ++nf) {
            int d = ds * 128 + nf * 16 + lr;
            ushort8 vf = *(const ushort8*)(Vg + (size_t)d * 4096 + (size_t)ktv * 2 + hi * 16);
#pragma unroll
            for (int mf = 0; mf < 4; ++mf) acc[mf][nf] = mfma16(pf[mf], vf, acc[mf][nf]);
        }
    };

    // prologue: K(0), K(1); S(0)
    prefetch_k(0);
    __syncthreads();                       // K0 landed (vmcnt drain)
    prefetch_k(1);                         // in flight across S(0)
    s_phase((const char*)&Klds[0][0]);

    for (int t = 1; t < 64; ++t) {
        softmax_store((t - 1) & 1);        // consumes s0c/s1c = S(t-1)
        __syncthreads();                   // P(t-1) visible; K(t) DMA drained
        if (t + 1 < 64) prefetch_k(t + 1); // safe: prior readers of buf behind barrier
        fused_phase(t, (t - 1) & 1, (t - 1) << 5);   // S(t) || PV(t-1)
    }

    // epilogue: tile 63
    softmax_store(1);
    __syncthreads();
    pv_phase(1, 63 << 5);

    // final l for all 128 rows -> LDS
    if (hi == 0) lred[wv * 16 + lr] = lrun;
    __syncthreads();

    const int b = bh >> 3, h = bh & 7;
#pragma unroll
    for (int mf = 0; mf < 4; ++mf) {
        f32x4 lv = *(const f32x4*)&lred[qh * 64 + mf * 16 + hi * 4];
        f32x4 inv;
#pragma unroll
        for (int r = 0; r < 4; ++r) inv[r] = 1.0f / lv[r];
#pragma unroll
        for (int nf = 0; nf < 8; ++nf) {
            int d = ds * 128 + nf * 16 + lr;
#pragma unroll
            for (int r = 0; r < 4; ++r) {
                int t = q0 + qh * 64 + mf * 16 + hi * 4 + r;
                O[((size_t)(b * 2048 + t)) * 4096 + h * 512 + d] = f2bf(acc[mf][nf][r] * inv[r]);
            }
        }
    }
}

// ---------- host ----------
extern "C" void kernel_launch(void* const* d_in, const int* in_sizes, int n_in,
                              void* d_out, int out_size, void* d_ws, size_t ws_size,
                              hipStream_t stream) {
    const float* x  = (const float*)d_in[0];
    const float* Wq = (const float*)d_in[1];
    const float* Wk = (const float*)d_in[2];
    const float* Wv = (const float*)d_in[3];
    const float* Wu = (const float*)d_in[4];
    const float* bu = (const float*)d_in[5];

    char* ws = (char*)d_ws;
    const size_t MB = 1ull << 20;
    u16* xb  = (u16*)(ws + 0);          // 4 MB  x as bf16 [4096][512]
    u16* Wqt = (u16*)(ws + 4 * MB);     // 3 x 4 MB: Wq^T,Wk^T,Wv^T bf16 [4096][512] contiguous
    u16* Wut = (u16*)(ws + 16 * MB);    // 4 MB  Wu^T bf16 [512][4096]
    u16* Qb  = (u16*)(ws + 20 * MB);    // 2 x 32 MB: Q,K [bh][t][d] (Q pre-scaled)
    u16* Kb  = (u16*)(ws + 52 * MB);
    u16* Vtb = (u16*)(ws + 116 * MB);   // 32 MB [bh][d][t] (written directly by gemm_qkv z=2)
    u16* Ob  = (u16*)(ws + 84 * MB);    // 32 MB [b*t][h*d]

    prep_kernel<<<4096, 256, 0, stream>>>(x, Wq, Wk, Wv, Wu, xb, Wqt, Wut);

    // 512^-0.5 * log2(e): softmax runs in base-2 (exp2f), fold conversion into Q scale
    const float s2 = 0.06375871593f;
    gemm_qkv<<<dim3(32, 32, 3), 256, 0, stream>>>(xb, Wqt, s2, Qb, Vtb);

    attn_kernel<<<256, 512, 0, stream>>>(Qb, Kb, Vtb, Ob);

    gemm_final<<<dim3(8, 32), 256, 0, stream>>>(Ob, Wut, bu, (float*)d_out, 4096);
}

// Round 12
// 457.077 us; speedup vs baseline: 1.0932x; 1.0932x over previous
//
#include <hip/hip_runtime.h>

typedef unsigned short u16;
typedef unsigned short ushort8 __attribute__((ext_vector_type(8)));
typedef unsigned short us4 __attribute__((ext_vector_type(4)));
typedef __bf16 bf16x8 __attribute__((ext_vector_type(8)));
typedef float f32x4 __attribute__((ext_vector_type(4)));

#define DEV static __device__ __forceinline__

// ---------- helpers ----------
DEV u16 f2bf(float f) {   // round-to-nearest-even f32 -> bf16
    unsigned int u = __builtin_bit_cast(unsigned int, f);
    u += 0x7FFFu + ((u >> 16) & 1u);
    return (u16)(u >> 16);
}

DEV f32x4 mfma16(ushort8 a, ushort8 b, f32x4 c) {
    return __builtin_amdgcn_mfma_f32_16x16x32_bf16((bf16x8)a, (bf16x8)b, c, 0, 0, 0);
}

DEV void gload_lds16(const void* g, void* l) {   // async global->LDS, dst = base + lane*16
    __builtin_amdgcn_global_load_lds(
        (const __attribute__((address_space(1))) void*)g,
        (__attribute__((address_space(3))) void*)l, 16, 0, 0);
}

// ---------- fused prep: x cvt + Wq/Wk/Wv transpose + Wu transpose (one launch) ----------
// flat grid 4096: [0,2048) x->bf16; [2048,3584) W{q,k,v}^T; [3584,4096) Wu^T.
__global__ void prep_kernel(const float* __restrict__ x,
                            const float* __restrict__ Wq, const float* __restrict__ Wk,
                            const float* __restrict__ Wv, const float* __restrict__ Wu,
                            u16* __restrict__ xb, u16* __restrict__ Wqt, u16* __restrict__ Wut) {
    __shared__ u16 tile[64][72];
    const int bid = blockIdx.x;

    if (bid < 2048) {                              // x fp32 -> bf16, vectorized
        int i = (bid * 256 + threadIdx.x) * 4;
        float4 f = *(const float4*)(x + i);
        us4 o;
        o.x = f2bf(f.x); o.y = f2bf(f.y); o.z = f2bf(f.z); o.w = f2bf(f.w);
        *(us4*)(xb + i) = o;
        return;
    }

    const float* in;
    u16* out;
    int R, C, c0, r0;
    if (bid < 3584) {                              // Wq/Wk/Wv [512][4096] -> ^T bf16
        int j = bid - 2048;
        int z = j >> 9, rem = j & 511;
        in = (z == 0) ? Wq : (z == 1) ? Wk : Wv;
        out = Wqt + (size_t)z * 2097152;           // 4 MB stride
        R = 512; C = 4096;
        c0 = (rem & 63) << 6; r0 = (rem >> 6) << 6;
    } else {                                       // Wu [4096][512] -> ^T bf16
        int k = bid - 3584;
        in = Wu; out = Wut;
        R = 4096; C = 512;
        c0 = (k & 7) << 6; r0 = (k >> 3) << 6;
    }
    int tx = threadIdx.x & 63, ty = threadIdx.x >> 6;
    for (int i = 0; i < 64; i += 4) {
        int r = i + ty;
        tile[r][tx] = f2bf(in[(size_t)(r0 + r) * C + c0 + tx]);
    }
    __syncthreads();
    for (int i = 0; i < 64; i += 4) {
        int r = i + ty;
        out[(size_t)(c0 + r) * R + r0 + tx] = tile[tx][r];
    }
}

// ---------- QKV GEMM (z-fused): C = xb @ W{q,k,v}t^T, 128x128 tile, Kc=512 ----------
// z selects weight + output; Q (z=0) pre-scaled by s2.
// z==2 (V) stores DIRECTLY TRANSPOSED to Vtb [bh][d][t]: packed 8B store.
__launch_bounds__(256, 3)
__global__ void gemm_qkv(const u16* __restrict__ A, const u16* __restrict__ Btbase,
                         float s2, u16* __restrict__ outbase, u16* __restrict__ vtb) {
    __shared__ u16 Asub[128 * 32];
    __shared__ u16 Bsub[128 * 32];
    const int Kc = 512;
    const u16* Bt = Btbase + (size_t)blockIdx.z * 2097152;     // 4 MB stride
    u16* out = outbase + (size_t)blockIdx.z * 16777216;        // 32 MB stride (z=0,1)
    const float scale = (blockIdx.z == 0) ? s2 : 1.0f;

    const int tid = threadIdx.x, lane = tid & 63, wv = tid >> 6;
    const int bm = blockIdx.y << 7, bn = blockIdx.x << 7;
    const int wr = (wv >> 1) << 6, wc = (wv & 1) << 6;
    const int lr = lane & 15, hi = lane >> 4;

    f32x4 acc[4][4] = {};

    int off0 = (wv * 2048 + lane * 16) >> 1;
    int row0 = off0 >> 5, k0e = off0 & 31;
    int off1 = off0 + 512;
    int row1 = off1 >> 5, k1e = off1 & 31;

    const u16* Ag0 = A + (size_t)(bm + row0) * Kc + k0e;
    const u16* Ag1 = A + (size_t)(bm + row1) * Kc + k1e;
    const u16* Bg0 = Bt + (size_t)(bn + row0) * Kc + k0e;
    const u16* Bg1 = Bt + (size_t)(bn + row1) * Kc + k1e;

    for (int kk = 0; kk < Kc; kk += 32) {
        __syncthreads();
        gload_lds16(Ag0 + kk, &Asub[wv * 1024]);
        gload_lds16(Ag1 + kk, &Asub[wv * 1024 + 512]);
        gload_lds16(Bg0 + kk, &Bsub[wv * 1024]);
        gload_lds16(Bg1 + kk, &Bsub[wv * 1024 + 512]);
        __syncthreads();

        ushort8 a[4], b[4];
#pragma unroll
        for (int m = 0; m < 4; ++m)
            a[m] = *(const ushort8*)&Asub[(wr + m * 16 + lr) * 32 + hi * 8];
#pragma unroll
        for (int n = 0; n < 4; ++n)
            b[n] = *(const ushort8*)&Bsub[(wc + n * 16 + lr) * 32 + hi * 8];
#pragma unroll
        for (int m = 0; m < 4; ++m)
#pragma unroll
            for (int n = 0; n < 4; ++n)
                acc[m][n] = mfma16(a[m], b[n], acc[m][n]);
    }

    if (blockIdx.z == 2) {
        // V: packed-transposed store to Vtb[bh][d][t]
#pragma unroll
        for (int m = 0; m < 4; ++m)
#pragma unroll
            for (int n = 0; n < 4; ++n) {
                int row0v = bm + wr + m * 16 + hi * 4;     // token = b*2048 + t0 (t0 % 4 == 0)
                int col   = bn + wc + n * 16 + lr;         // h*512 + d
                int b = row0v >> 11, t0 = row0v & 2047;
                int h = col >> 9, d = col & 511;
                us4 pk;
#pragma unroll
                for (int r = 0; r < 4; ++r) pk[r] = f2bf(acc[m][n][r]);
                *(us4*)&vtb[(((size_t)(b * 8 + h) * 512 + d) << 11) + t0] = pk;
            }
    } else {
#pragma unroll
        for (int m = 0; m < 4; ++m)
#pragma unroll
            for (int n = 0; n < 4; ++n)
#pragma unroll
                for (int r = 0; r < 4; ++r) {
                    int row = bm + wr + m * 16 + hi * 4 + r;   // token index b*2048+t
                    int col = bn + wc + n * 16 + lr;           // h*512+d
                    float v = acc[m][n][r] * scale;
                    size_t dst = ((size_t)((row >> 11) * 8 + (col >> 9)) * 2048 + (row & 2047)) * 512
                                 + (col & 511);
                    out[dst] = f2bf(v);
                }
    }
}

// ---------- final GEMM: out[4096][512] = Ob[4096][4096] @ Wut[512][4096]^T + bu ----------
// BM=128, BN=64 -> grid (8,32) = 256 blocks (full chip).
__launch_bounds__(256, 3)
__global__ void gemm_final(const u16* __restrict__ A, const u16* __restrict__ Bt,
                           const float* __restrict__ bias, float* __restrict__ out, int Kc) {
    __shared__ u16 Asub[128 * 32];
    __shared__ u16 Bsub[64 * 32];
    const int tid = threadIdx.x, lane = tid & 63, wv = tid >> 6;
    const int bm = blockIdx.y << 7, bn = blockIdx.x << 6;
    const int wr = (wv >> 1) << 6, wc = (wv & 1) << 5;
    const int lr = lane & 15, hi = lane >> 4;

    f32x4 acc[4][2] = {};

    // staging: 12 segs x 1KB (A: 0-7, B: 8-11); wave wv stages segs wv*3..wv*3+2
    const u16* gsrc[3];
    u16* ldst[3];
#pragma unroll
    for (int j = 0; j < 3; ++j) {
        int g = wv * 3 + j;
        int off = g * 512 + lane * 8;
        if (g < 8) {
            int row = off >> 5, k = off & 31;
            gsrc[j] = A + (size_t)(bm + row) * Kc + k;
            ldst[j] = &Asub[g * 512];
        } else {
            int off2 = off - 4096;
            int row = off2 >> 5, k = off2 & 31;
            gsrc[j] = Bt + (size_t)(bn + row) * Kc + k;
            ldst[j] = &Bsub[(g - 8) * 512];
        }
    }

    for (int kk = 0; kk < Kc; kk += 32) {
        __syncthreads();
#pragma unroll
        for (int j = 0; j < 3; ++j) gload_lds16(gsrc[j] + kk, ldst[j]);
        __syncthreads();

        ushort8 a[4], b[2];
#pragma unroll
        for (int m = 0; m < 4; ++m)
            a[m] = *(const ushort8*)&Asub[(wr + m * 16 + lr) * 32 + hi * 8];
#pragma unroll
        for (int n = 0; n < 2; ++n)
            b[n] = *(const ushort8*)&Bsub[(wc + n * 16 + lr) * 32 + hi * 8];
#pragma unroll
        for (int m = 0; m < 4; ++m)
#pragma unroll
            for (int n = 0; n < 2; ++n)
                acc[m][n] = mfma16(a[m], b[n], acc[m][n]);
    }

#pragma unroll
    for (int m = 0; m < 4; ++m)
#pragma unroll
        for (int n = 0; n < 2; ++n)
#pragma unroll
            for (int r = 0; r < 4; ++r) {
                int row = bm + wr + m * 16 + hi * 4 + r;
                int col = bn + wc + n * 16 + lr;
                out[(size_t)row * 512 + col] = acc[m][n][r] + bias[col];
            }
}

// ---------- flash attention (v7 attn, FROZEN — verified local optimum) ----------
// T15 att[2] pipelining: iter t issues S(t) MFMAs, runs softmax(t-1) in their shadow,
// one barrier, then PV(t-1). K dbuf via global_load_lds (pre-swizzled source).
// DO NOT move V loads (v3 pre-barrier, v8 batch-hoist, v11 dual-stream interleave
// all regressed); inline per-nf loads let the compiler roll load(nf+1) under MFMAs(nf).
__launch_bounds__(512, 2)
__global__ void attn_kernel(const u16* __restrict__ Q, const u16* __restrict__ K,
                            const u16* __restrict__ Vt, u16* __restrict__ O) {
    __shared__ u16 Klds[2][32 * 512];            // 2 x 32KB, XOR-swizzled rows
    __shared__ u16 Plds[2][128 * 40];            // [q][32 keys + 8 pad]
    __shared__ __align__(16) float red[2][128];  // per-row alpha
    __shared__ __align__(16) float lred[128];    // final l
    __shared__ int rflag[2][8];                  // per-wave "some row rescaled"

    const int tid = threadIdx.x, lane = tid & 63, wv = tid >> 6;
    const int lr = lane & 15, hi = lane >> 4;
    const int qh = wv >> 2, ds = wv & 3;         // PV decomposition

    // XCD-chunked bijective swizzle: 256 blocks = 8 XCDs x 32; 2 bh per XCD chunk
    const int flat = blockIdx.x;
    const int nid = (flat & 7) * 32 + (flat >> 3);
    const int bh = nid >> 4;
    const int q0 = (nid & 15) << 7;

    // Q fragments (B-operand: col=lane&15 -> q-row wv*16+lr, k-slice hi*8..+8)
    ushort8 qf[16];
    {
        const char* Qg = (const char*)(Q + ((size_t)bh * 2048 + q0 + wv * 16 + lr) * 512) + hi * 16;
#pragma unroll
        for (int ks = 0; ks < 16; ++ks) qf[ks] = *(const ushort8*)(Qg + ks * 64);
    }

    f32x4 acc[4][8] = {};   // [q 16-block within 64-row half][d 16-frag within 128-wide slice]
    float mrun = -1e30f, lrun = 0.f;   // per-lane, q = wv*16+lr (replicated over hi), base-2

    const char* Kg = (const char*)(K + (size_t)bh * 2048 * 512);
    const char* Vg = (const char*)(Vt + (size_t)bh * 512 * 2048);

    // S-phase: 32 MFMAs into two chains (keys lr / lr+16), zero-started
    auto s_phase = [&](const char* Kb, f32x4& s0, f32x4& s1) {
        s0 = (f32x4){0.f, 0.f, 0.f, 0.f};
        s1 = (f32x4){0.f, 0.f, 0.f, 0.f};
#pragma unroll
        for (int ks = 0; ks < 16; ++ks) {
            int swz = (ks * 64 + hi * 16) ^ ((lr & 7) << 4);
            ushort8 kf0 = *(const ushort8*)(Kb + lr * 1024 + swz);
            ushort8 kf1 = *(const ushort8*)(Kb + (lr + 16) * 1024 + swz);
            s0 = mfma16(kf0, qf[ks], s0);
            s1 = mfma16(kf1, qf[ks], s1);
        }
    };

    // softmax on a finished S pair; writes P/alpha/flag into slot pcb
    auto softmax_store = [&](const f32x4& s0, const f32x4& s1, int pcb) {
        float mx = fmaxf(fmaxf(fmaxf(s0[0], s0[1]), fmaxf(s0[2], s0[3])),
                         fmaxf(fmaxf(s1[0], s1[1]), fmaxf(s1[2], s1[3])));
        mx = fmaxf(mx, __shfl_xor(mx, 16));
        mx = fmaxf(mx, __shfl_xor(mx, 32));
        float a = 1.0f;
        bool upd = false;
        if (mx > mrun + 11.5f) { a = exp2f(mrun - mx); mrun = mx; upd = true; }   // defer-max
        float p[8];
#pragma unroll
        for (int r = 0; r < 4; ++r) {
            p[r]     = exp2f(s0[r] - mrun);
            p[4 + r] = exp2f(s1[r] - mrun);
        }
        float ps = ((p[0] + p[1]) + (p[2] + p[3])) + ((p[4] + p[5]) + (p[6] + p[7]));
        ps += __shfl_xor(ps, 16);
        ps += __shfl_xor(ps, 32);
        lrun = lrun * a + ps;

        const int qr = wv * 16 + lr;
        char* Pb = (char*)&Plds[pcb][0] + qr * 80;
        uint2 w01, w23;
        w01.x = (unsigned)f2bf(p[0]) | ((unsigned)f2bf(p[1]) << 16);
        w01.y = (unsigned)f2bf(p[2]) | ((unsigned)f2bf(p[3]) << 16);
        w23.x = (unsigned)f2bf(p[4]) | ((unsigned)f2bf(p[5]) << 16);
        w23.y = (unsigned)f2bf(p[6]) | ((unsigned)f2bf(p[7]) << 16);
        *(uint2*)(Pb + hi * 8) = w01;
        *(uint2*)(Pb + 32 + hi * 8) = w23;
        if (hi == 0) red[pcb][qr] = a;
        if (lane == 0) rflag[pcb][wv] = __any(upd) ? 1 : 0;
    };

    // rescale (defer-max gated) + PV for tile whose P sits in slot pcb, V tile at key ktv
    auto pv_phase = [&](int pcb, int ktv) {
        int anyupd = rflag[pcb][0] | rflag[pcb][1] | rflag[pcb][2] | rflag[pcb][3]
                   | rflag[pcb][4] | rflag[pcb][5] | rflag[pcb][6] | rflag[pcb][7];
        if (anyupd) {
#pragma unroll
            for (int mf = 0; mf < 4; ++mf) {
                f32x4 a4 = *(const f32x4*)&red[pcb][qh * 64 + mf * 16 + hi * 4];
#pragma unroll
                for (int nf = 0; nf < 8; ++nf)
#pragma unroll
                    for (int r = 0; r < 4; ++r) acc[mf][nf][r] *= a4[r];
            }
        }
        ushort8 pf[4];
#pragma unroll
        for (int mf = 0; mf < 4; ++mf)
            pf[mf] = *(const ushort8*)((const char*)&Plds[pcb][0]
                                       + (qh * 64 + mf * 16 + lr) * 80 + hi * 16);
        __builtin_amdgcn_s_setprio(1);
#pragma unroll
        for (int nf = 0; nf < 8; ++nf) {
            int d = ds * 128 + nf * 16 + lr;
            ushort8 vf = *(const ushort8*)(Vg + (size_t)d * 4096 + (size_t)ktv * 2 + hi * 16);
#pragma unroll
            for (int mf = 0; mf < 4; ++mf) acc[mf][nf] = mfma16(pf[mf], vf, acc[mf][nf]);
        }
        __builtin_amdgcn_s_setprio(0);
    };

    auto prefetch_k = [&](int tt) {   // stage K(tt) into buf tt&1
        const char* Kgt = Kg + (size_t)tt * 32 * 1024;
#pragma unroll
        for (int r4 = 0; r4 < 4; ++r4) {
            int r = wv * 4 + r4;
            gload_lds16(Kgt + (size_t)r * 1024 + ((lane ^ (r & 7)) << 4),
                        &Klds[tt & 1][(size_t)r * 512]);
        }
    };

    f32x4 s0c, s1c, s0p, s1p;

    // prologue: K(0) -> buf0
    prefetch_k(0);
    __syncthreads();                       // K0 ready

    // peeled iter 0: prefetch K(1), S(0); no softmax/PV yet
    prefetch_k(1);
    s_phase((const char*)&Klds[0][0], s0c, s1c);
    __syncthreads();                       // K1 DMA drained; S(0) reads of buf0 done

    for (int t = 1; t < 64; ++t) {
        if (t + 1 < 64) prefetch_k(t + 1);       // -> buf (t+1)&1 (= buf read by S(t-1), done)

        s0p = s0c; s1p = s1c;                     // retire S(t-1) results
        s_phase((const char*)&Klds[t & 1][0], s0c, s1c);   // S(t) in flight...
        softmax_store(s0p, s1p, (t - 1) & 1);     // ...while softmax(t-1) runs on VALU

        __syncthreads();   // P(t-1)/alpha visible; K(t+1) drained; buf[t&1] reads done

        pv_phase((t - 1) & 1, (t - 1) << 5);
    }

    // epilogue: tile 63
    softmax_store(s0c, s1c, 1);
    __syncthreads();
    pv_phase(1, 63 << 5);

    // final l for all 128 rows -> LDS
    if (hi == 0) lred[wv * 16 + lr] = lrun;
    __syncthreads();

    const int b = bh >> 3, h = bh & 7;
#pragma unroll
    for (int mf = 0; mf < 4; ++mf) {
        f32x4 lv = *(const f32x4*)&lred[qh * 64 + mf * 16 + hi * 4];
        f32x4 inv;
#pragma unroll
        for (int r = 0; r < 4; ++r) inv[r] = 1.0f / lv[r];
#pragma unroll
        for (int nf = 0; nf < 8; ++nf) {
            int d = ds * 128 + nf * 16 + lr;
#pragma unroll
            for (int r = 0; r < 4; ++r) {
                int t = q0 + qh * 64 + mf * 16 + hi * 4 + r;
                O[((size_t)(b * 2048 + t)) * 4096 + h * 512 + d] = f2bf(acc[mf][nf][r] * inv[r]);
            }
        }
    }
}

// ---------- host ----------
extern "C" void kernel_launch(void* const* d_in, const int* in_sizes, int n_in,
                              void* d_out, int out_size, void* d_ws, size_t ws_size,
                              hipStream_t stream) {
    const float* x  = (const float*)d_in[0];
    const float* Wq = (const float*)d_in[1];
    const float* Wk = (const float*)d_in[2];
    const float* Wv = (const float*)d_in[3];
    const float* Wu = (const float*)d_in[4];
    const float* bu = (const float*)d_in[5];

    char* ws = (char*)d_ws;
    const size_t MB = 1ull << 20;
    u16* xb  = (u16*)(ws + 0);          // 4 MB  x as bf16 [4096][512]
    u16* Wqt = (u16*)(ws + 4 * MB);     // 3 x 4 MB: Wq^T,Wk^T,Wv^T bf16 [4096][512] contiguous
    u16* Wut = (u16*)(ws + 16 * MB);    // 4 MB  Wu^T bf16 [512][4096]
    u16* Qb  = (u16*)(ws + 20 * MB);    // 2 x 32 MB: Q,K [bh][t][d] (Q pre-scaled)
    u16* Kb  = (u16*)(ws + 52 * MB);
    u16* Vtb = (u16*)(ws + 116 * MB);   // 32 MB [bh][d][t] (written directly by gemm_qkv z=2)
    u16* Ob  = (u16*)(ws + 84 * MB);    // 32 MB [b*t][h*d]

    prep_kernel<<<4096, 256, 0, stream>>>(x, Wq, Wk, Wv, Wu, xb, Wqt, Wut);

    // 512^-0.5 * log2(e): softmax runs in base-2 (exp2f), fold conversion into Q scale
    const float s2 = 0.06375871593f;
    gemm_qkv<<<dim3(32, 32, 3), 256, 0, stream>>>(xb, Wqt, s2, Qb, Vtb);

    attn_kernel<<<256, 512, 0, stream>>>(Qb, Kb, Vtb, Ob);

    gemm_final<<<dim3(8, 32), 256, 0, stream>>>(Ob, Wut, bu, (float*)d_out, 4096);
}

// Round 13
// 456.973 us; speedup vs baseline: 1.0935x; 1.0002x over previous
//
#include <hip/hip_runtime.h>

typedef unsigned short u16;
typedef unsigned short ushort8 __attribute__((ext_vector_type(8)));
typedef unsigned short us4 __attribute__((ext_vector_type(4)));
typedef __bf16 bf16x8 __attribute__((ext_vector_type(8)));
typedef float f32x4 __attribute__((ext_vector_type(4)));

#define DEV static __device__ __forceinline__

// ---------- helpers ----------
DEV u16 f2bf(float f) {   // round-to-nearest-even f32 -> bf16
    unsigned int u = __builtin_bit_cast(unsigned int, f);
    u += 0x7FFFu + ((u >> 16) & 1u);
    return (u16)(u >> 16);
}

DEV f32x4 mfma16(ushort8 a, ushort8 b, f32x4 c) {
    return __builtin_amdgcn_mfma_f32_16x16x32_bf16((bf16x8)a, (bf16x8)b, c, 0, 0, 0);
}

DEV void gload_lds16(const void* g, void* l) {   // async global->LDS, dst = base + lane*16
    __builtin_amdgcn_global_load_lds(
        (const __attribute__((address_space(1))) void*)g,
        (__attribute__((address_space(3))) void*)l, 16, 0, 0);
}

// ---------- fused prep: x cvt + Wq/Wk/Wv transpose + Wu transpose (one launch) ----------
// flat grid 4096: [0,2048) x->bf16; [2048,3584) W{q,k,v}^T; [3584,4096) Wu^T.
__global__ void prep_kernel(const float* __restrict__ x,
                            const float* __restrict__ Wq, const float* __restrict__ Wk,
                            const float* __restrict__ Wv, const float* __restrict__ Wu,
                            u16* __restrict__ xb, u16* __restrict__ Wqt, u16* __restrict__ Wut) {
    __shared__ u16 tile[64][72];
    const int bid = blockIdx.x;

    if (bid < 2048) {                              // x fp32 -> bf16, vectorized
        int i = (bid * 256 + threadIdx.x) * 4;
        float4 f = *(const float4*)(x + i);
        us4 o;
        o.x = f2bf(f.x); o.y = f2bf(f.y); o.z = f2bf(f.z); o.w = f2bf(f.w);
        *(us4*)(xb + i) = o;
        return;
    }

    const float* in;
    u16* out;
    int R, C, c0, r0;
    if (bid < 3584) {                              // Wq/Wk/Wv [512][4096] -> ^T bf16
        int j = bid - 2048;
        int z = j >> 9, rem = j & 511;
        in = (z == 0) ? Wq : (z == 1) ? Wk : Wv;
        out = Wqt + (size_t)z * 2097152;           // 4 MB stride
        R = 512; C = 4096;
        c0 = (rem & 63) << 6; r0 = (rem >> 6) << 6;
    } else {                                       // Wu [4096][512] -> ^T bf16
        int k = bid - 3584;
        in = Wu; out = Wut;
        R = 4096; C = 512;
        c0 = (k & 7) << 6; r0 = (k >> 3) << 6;
    }
    int tx = threadIdx.x & 63, ty = threadIdx.x >> 6;
    for (int i = 0; i < 64; i += 4) {
        int r = i + ty;
        tile[r][tx] = f2bf(in[(size_t)(r0 + r) * C + c0 + tx]);
    }
    __syncthreads();
    for (int i = 0; i < 64; i += 4) {
        int r = i + ty;
        out[(size_t)(c0 + r) * R + r0 + tx] = tile[tx][r];
    }
}

// ---------- QKV GEMM (z-fused): C = xb @ W{q,k,v}t^T, 128x128 tile, BK=64, Kc=512 ----------
// BK 32->64: halves the per-barrier vmcnt(0) drains (32 -> 16 barriers/block) while
// keeping 3 blocks/CU (32 KB LDS). 128B LDS rows would be 16-lanes/bank-slot on the
// ds_read_b128 side, so rows carry the attn-verified XOR swizzle: linear DMA dest +
// inverse-swizzled GLOBAL source chunk + same-XOR read offset (rule: both-sides-or-neither).
// K accumulation order unchanged (k=0..31,32..63,...) -> bit-identical output.
// z==2 (V) stores DIRECTLY TRANSPOSED to Vtb [bh][d][t]: packed 8B store.
__launch_bounds__(256, 3)
__global__ void gemm_qkv(const u16* __restrict__ A, const u16* __restrict__ Btbase,
                         float s2, u16* __restrict__ outbase, u16* __restrict__ vtb) {
    __shared__ u16 Asub[128 * 64];   // 16 KB, XOR-swizzled rows of 128 B
    __shared__ u16 Bsub[128 * 64];   // 16 KB
    const int Kc = 512;
    const u16* Bt = Btbase + (size_t)blockIdx.z * 2097152;     // 4 MB stride
    u16* out = outbase + (size_t)blockIdx.z * 16777216;        // 32 MB stride (z=0,1)
    const float scale = (blockIdx.z == 0) ? s2 : 1.0f;

    const int tid = threadIdx.x, lane = tid & 63, wv = tid >> 6;
    const int bm = blockIdx.y << 7, bn = blockIdx.x << 7;
    const int wr = (wv >> 1) << 6, wc = (wv & 1) << 6;
    const int lr = lane & 15, hi = lane >> 4;

    f32x4 acc[4][4] = {};

    // staging: wave wv owns rows [wv*32, wv*32+32) of A and B; 4 gloads each (1KB = 8 rows).
    // lane l -> row srow=l>>3, 16B-slot l&7; source chunk pre-swizzled by row&7 (= srow).
    const int srow = lane >> 3;
    const int schunk = ((lane & 7) ^ srow) * 8;    // element offset of this lane's 16B chunk
    const u16* Ag[4];
    const u16* Bg[4];
#pragma unroll
    for (int g = 0; g < 4; ++g) {
        int row = wv * 32 + g * 8 + srow;
        Ag[g] = A + (size_t)(bm + row) * Kc + schunk;
        Bg[g] = Bt + (size_t)(bn + row) * Kc + schunk;
    }

    for (int kk = 0; kk < Kc; kk += 64) {
        __syncthreads();
#pragma unroll
        for (int g = 0; g < 4; ++g) {
            gload_lds16(Ag[g] + kk, &Asub[(wv * 32 + g * 8) * 64]);
            gload_lds16(Bg[g] + kk, &Bsub[(wv * 32 + g * 8) * 64]);
        }
        __syncthreads();

#pragma unroll
        for (int kh = 0; kh < 2; ++kh) {           // two K=32 halves, same accumulation order
            const int coff = (kh * 64 + hi * 16) ^ ((lr & 7) << 4);   // swizzled byte-in-row
            ushort8 a[4], b[4];
#pragma unroll
            for (int m = 0; m < 4; ++m)
                a[m] = *(const ushort8*)((const char*)Asub + (wr + m * 16 + lr) * 128 + coff);
#pragma unroll
            for (int n = 0; n < 4; ++n)
                b[n] = *(const ushort8*)((const char*)Bsub + (wc + n * 16 + lr) * 128 + coff);
#pragma unroll
            for (int m = 0; m < 4; ++m)
#pragma unroll
                for (int n = 0; n < 4; ++n)
                    acc[m][n] = mfma16(a[m], b[n], acc[m][n]);
        }
    }

    if (blockIdx.z == 2) {
        // V: packed-transposed store to Vtb[bh][d][t]
#pragma unroll
        for (int m = 0; m < 4; ++m)
#pragma unroll
            for (int n = 0; n < 4; ++n) {
                int row0v = bm + wr + m * 16 + hi * 4;     // token = b*2048 + t0 (t0 % 4 == 0)
                int col   = bn + wc + n * 16 + lr;         // h*512 + d
                int b = row0v >> 11, t0 = row0v & 2047;
                int h = col >> 9, d = col & 511;
                us4 pk;
#pragma unroll
                for (int r = 0; r < 4; ++r) pk[r] = f2bf(acc[m][n][r]);
                *(us4*)&vtb[(((size_t)(b * 8 + h) * 512 + d) << 11) + t0] = pk;
            }
    } else {
#pragma unroll
        for (int m = 0; m < 4; ++m)
#pragma unroll
            for (int n = 0; n < 4; ++n)
#pragma unroll
                for (int r = 0; r < 4; ++r) {
                    int row = bm + wr + m * 16 + hi * 4 + r;   // token index b*2048+t
                    int col = bn + wc + n * 16 + lr;           // h*512+d
                    float v = acc[m][n][r] * scale;
                    size_t dst = ((size_t)((row >> 11) * 8 + (col >> 9)) * 2048 + (row & 2047)) * 512
                                 + (col & 511);
                    out[dst] = f2bf(v);
                }
    }
}

// ---------- final GEMM: out[4096][512] = Ob[4096][4096] @ Wut[512][4096]^T + bu ----------
// BM=128, BN=64, BK=64 (barriers 256 -> 128), grid (8,32) = 256 blocks (full chip).
// Same XOR-swizzled 128B-row staging as gemm_qkv. 24 segs x 1KB (A:0-15, B:16-23),
// wave wv stages segs wv*6..wv*6+5.
__launch_bounds__(256, 3)
__global__ void gemm_final(const u16* __restrict__ A, const u16* __restrict__ Bt,
                           const float* __restrict__ bias, float* __restrict__ out, int Kc) {
    __shared__ u16 Asub[128 * 64];   // 16 KB
    __shared__ u16 Bsub[64 * 64];    // 8 KB
    const int tid = threadIdx.x, lane = tid & 63, wv = tid >> 6;
    const int bm = blockIdx.y << 7, bn = blockIdx.x << 6;
    const int wr = (wv >> 1) << 6, wc = (wv & 1) << 5;
    const int lr = lane & 15, hi = lane >> 4;

    f32x4 acc[4][2] = {};

    const int srow = lane >> 3;
    const int schunk = ((lane & 7) ^ srow) * 8;
    const u16* gsrc[6];
    u16* ldst[6];
#pragma unroll
    for (int j = 0; j < 6; ++j) {
        int g = wv * 6 + j;
        if (g < 16) {                      // A segs: rows g*8 + srow
            int row = g * 8 + srow;
            gsrc[j] = A + (size_t)(bm + row) * Kc + schunk;
            ldst[j] = &Asub[g * 8 * 64];
        } else {                           // B segs: rows (g-16)*8 + srow
            int row = (g - 16) * 8 + srow;
            gsrc[j] = Bt + (size_t)(bn + row) * Kc + schunk;
            ldst[j] = &Bsub[(g - 16) * 8 * 64];
        }
    }

    for (int kk = 0; kk < Kc; kk += 64) {
        __syncthreads();
#pragma unroll
        for (int j = 0; j < 6; ++j) gload_lds16(gsrc[j] + kk, ldst[j]);
        __syncthreads();

#pragma unroll
        for (int kh = 0; kh < 2; ++kh) {
            const int coff = (kh * 64 + hi * 16) ^ ((lr & 7) << 4);
            ushort8 a[4], b[2];
#pragma unroll
            for (int m = 0; m < 4; ++m)
                a[m] = *(const ushort8*)((const char*)Asub + (wr + m * 16 + lr) * 128 + coff);
#pragma unroll
            for (int n = 0; n < 2; ++n)
                b[n] = *(const ushort8*)((const char*)Bsub + (wc + n * 16 + lr) * 128 + coff);
#pragma unroll
            for (int m = 0; m < 4; ++m)
#pragma unroll
                for (int n = 0; n < 2; ++n)
                    acc[m][n] = mfma16(a[m], b[n], acc[m][n]);
        }
    }

#pragma unroll
    for (int m = 0; m < 4; ++m)
#pragma unroll
        for (int n = 0; n < 2; ++n)
#pragma unroll
            for (int r = 0; r < 4; ++r) {
                int row = bm + wr + m * 16 + hi * 4 + r;
                int col = bn + wc + n * 16 + lr;
                out[(size_t)row * 512 + col] = acc[m][n][r] + bias[col];
            }
}

// ---------- flash attention (v7 attn, FROZEN — verified local optimum) ----------
// T15 att[2] pipelining: iter t issues S(t) MFMAs, runs softmax(t-1) in their shadow,
// one barrier, then PV(t-1). K dbuf via global_load_lds (pre-swizzled source).
// DO NOT move V loads (v3 pre-barrier, v8 batch-hoist, v11 dual-stream interleave
// all regressed); inline per-nf loads let the compiler roll load(nf+1) under MFMAs(nf).
__launch_bounds__(512, 2)
__global__ void attn_kernel(const u16* __restrict__ Q, const u16* __restrict__ K,
                            const u16* __restrict__ Vt, u16* __restrict__ O) {
    __shared__ u16 Klds[2][32 * 512];            // 2 x 32KB, XOR-swizzled rows
    __shared__ u16 Plds[2][128 * 40];            // [q][32 keys + 8 pad]
    __shared__ __align__(16) float red[2][128];  // per-row alpha
    __shared__ __align__(16) float lred[128];    // final l
    __shared__ int rflag[2][8];                  // per-wave "some row rescaled"

    const int tid = threadIdx.x, lane = tid & 63, wv = tid >> 6;
    const int lr = lane & 15, hi = lane >> 4;
    const int qh = wv >> 2, ds = wv & 3;         // PV decomposition

    // XCD-chunked bijective swizzle: 256 blocks = 8 XCDs x 32; 2 bh per XCD chunk
    const int flat = blockIdx.x;
    const int nid = (flat & 7) * 32 + (flat >> 3);
    const int bh = nid >> 4;
    const int q0 = (nid & 15) << 7;

    // Q fragments (B-operand: col=lane&15 -> q-row wv*16+lr, k-slice hi*8..+8)
    ushort8 qf[16];
    {
        const char* Qg = (const char*)(Q + ((size_t)bh * 2048 + q0 + wv * 16 + lr) * 512) + hi * 16;
#pragma unroll
        for (int ks = 0; ks < 16; ++ks) qf[ks] = *(const ushort8*)(Qg + ks * 64);
    }

    f32x4 acc[4][8] = {};   // [q 16-block within 64-row half][d 16-frag within 128-wide slice]
    float mrun = -1e30f, lrun = 0.f;   // per-lane, q = wv*16+lr (replicated over hi), base-2

    const char* Kg = (const char*)(K + (size_t)bh * 2048 * 512);
    const char* Vg = (const char*)(Vt + (size_t)bh * 512 * 2048);

    // S-phase: 32 MFMAs into two chains (keys lr / lr+16), zero-started
    auto s_phase = [&](const char* Kb, f32x4& s0, f32x4& s1) {
        s0 = (f32x4){0.f, 0.f, 0.f, 0.f};
        s1 = (f32x4){0.f, 0.f, 0.f, 0.f};
#pragma unroll
        for (int ks = 0; ks < 16; ++ks) {
            int swz = (ks * 64 + hi * 16) ^ ((lr & 7) << 4);
            ushort8 kf0 = *(const ushort8*)(Kb + lr * 1024 + swz);
            ushort8 kf1 = *(const ushort8*)(Kb + (lr + 16) * 1024 + swz);
            s0 = mfma16(kf0, qf[ks], s0);
            s1 = mfma16(kf1, qf[ks], s1);
        }
    };

    // softmax on a finished S pair; writes P/alpha/flag into slot pcb
    auto softmax_store = [&](const f32x4& s0, const f32x4& s1, int pcb) {
        float mx = fmaxf(fmaxf(fmaxf(s0[0], s0[1]), fmaxf(s0[2], s0[3])),
                         fmaxf(fmaxf(s1[0], s1[1]), fmaxf(s1[2], s1[3])));
        mx = fmaxf(mx, __shfl_xor(mx, 16));
        mx = fmaxf(mx, __shfl_xor(mx, 32));
        float a = 1.0f;
        bool upd = false;
        if (mx > mrun + 11.5f) { a = exp2f(mrun - mx); mrun = mx; upd = true; }   // defer-max
        float p[8];
#pragma unroll
        for (int r = 0; r < 4; ++r) {
            p[r]     = exp2f(s0[r] - mrun);
            p[4 + r] = exp2f(s1[r] - mrun);
        }
        float ps = ((p[0] + p[1]) + (p[2] + p[3])) + ((p[4] + p[5]) + (p[6] + p[7]));
        ps += __shfl_xor(ps, 16);
        ps += __shfl_xor(ps, 32);
        lrun = lrun * a + ps;

        const int qr = wv * 16 + lr;
        char* Pb = (char*)&Plds[pcb][0] + qr * 80;
        uint2 w01, w23;
        w01.x = (unsigned)f2bf(p[0]) | ((unsigned)f2bf(p[1]) << 16);
        w01.y = (unsigned)f2bf(p[2]) | ((unsigned)f2bf(p[3]) << 16);
        w23.x = (unsigned)f2bf(p[4]) | ((unsigned)f2bf(p[5]) << 16);
        w23.y = (unsigned)f2bf(p[6]) | ((unsigned)f2bf(p[7]) << 16);
        *(uint2*)(Pb + hi * 8) = w01;
        *(uint2*)(Pb + 32 + hi * 8) = w23;
        if (hi == 0) red[pcb][qr] = a;
        if (lane == 0) rflag[pcb][wv] = __any(upd) ? 1 : 0;
    };

    // rescale (defer-max gated) + PV for tile whose P sits in slot pcb, V tile at key ktv
    auto pv_phase = [&](int pcb, int ktv) {
        int anyupd = rflag[pcb][0] | rflag[pcb][1] | rflag[pcb][2] | rflag[pcb][3]
                   | rflag[pcb][4] | rflag[pcb][5] | rflag[pcb][6] | rflag[pcb][7];
        if (anyupd) {
#pragma unroll
            for (int mf = 0; mf < 4; ++mf) {
                f32x4 a4 = *(const f32x4*)&red[pcb][qh * 64 + mf * 16 + hi * 4];
#pragma unroll
                for (int nf = 0; nf < 8; ++nf)
#pragma unroll
                    for (int r = 0; r < 4; ++r) acc[mf][nf][r] *= a4[r];
            }
        }
        ushort8 pf[4];
#pragma unroll
        for (int mf = 0; mf < 4; ++mf)
            pf[mf] = *(const ushort8*)((const char*)&Plds[pcb][0]
                                       + (qh * 64 + mf * 16 + lr) * 80 + hi * 16);
        __builtin_amdgcn_s_setprio(1);
#pragma unroll
        for (int nf = 0; nf < 8; ++nf) {
            int d = ds * 128 + nf * 16 + lr;
            ushort8 vf = *(const ushort8*)(Vg + (size_t)d * 4096 + (size_t)ktv * 2 + hi * 16);
#pragma unroll
            for (int mf = 0; mf < 4; ++mf) acc[mf][nf] = mfma16(pf[mf], vf, acc[mf][nf]);
        }
        __builtin_amdgcn_s_setprio(0);
    };

    auto prefetch_k = [&](int tt) {   // stage K(tt) into buf tt&1
        const char* Kgt = Kg + (size_t)tt * 32 * 1024;
#pragma unroll
        for (int r4 = 0; r4 < 4; ++r4) {
            int r = wv * 4 + r4;
            gload_lds16(Kgt + (size_t)r * 1024 + ((lane ^ (r & 7)) << 4),
                        &Klds[tt & 1][(size_t)r * 512]);
        }
    };

    f32x4 s0c, s1c, s0p, s1p;

    // prologue: K(0) -> buf0
    prefetch_k(0);
    __syncthreads();                       // K0 ready

    // peeled iter 0: prefetch K(1), S(0); no softmax/PV yet
    prefetch_k(1);
    s_phase((const char*)&Klds[0][0], s0c, s1c);
    __syncthreads();                       // K1 DMA drained; S(0) reads of buf0 done

    for (int t = 1; t < 64; ++t) {
        if (t + 1 < 64) prefetch_k(t + 1);       // -> buf (t+1)&1 (= buf read by S(t-1), done)

        s0p = s0c; s1p = s1c;                     // retire S(t-1) results
        s_phase((const char*)&Klds[t & 1][0], s0c, s1c);   // S(t) in flight...
        softmax_store(s0p, s1p, (t - 1) & 1);     // ...while softmax(t-1) runs on VALU

        __syncthreads();   // P(t-1)/alpha visible; K(t+1) drained; buf[t&1] reads done

        pv_phase((t - 1) & 1, (t - 1) << 5);
    }

    // epilogue: tile 63
    softmax_store(s0c, s1c, 1);
    __syncthreads();
    pv_phase(1, 63 << 5);

    // final l for all 128 rows -> LDS
    if (hi == 0) lred[wv * 16 + lr] = lrun;
    __syncthreads();

    const int b = bh >> 3, h = bh & 7;
#pragma unroll
    for (int mf = 0; mf < 4; ++mf) {
        f32x4 lv = *(const f32x4*)&lred[qh * 64 + mf * 16 + hi * 4];
        f32x4 inv;
#pragma unroll
        for (int r = 0; r < 4; ++r) inv[r] = 1.0f / lv[r];
#pragma unroll
        for (int nf = 0; nf < 8; ++nf) {
            int d = ds * 128 + nf * 16 + lr;
#pragma unroll
            for (int r = 0; r < 4; ++r) {
                int t = q0 + qh * 64 + mf * 16 + hi * 4 + r;
                O[((size_t)(b * 2048 + t)) * 4096 + h * 512 + d] = f2bf(acc[mf][nf][r] * inv[r]);
            }
        }
    }
}

// ---------- host ----------
extern "C" void kernel_launch(void* const* d_in, const int* in_sizes, int n_in,
                              void* d_out, int out_size, void* d_ws, size_t ws_size,
                              hipStream_t stream) {
    const float* x  = (const float*)d_in[0];
    const float* Wq = (const float*)d_in[1];
    const float* Wk = (const float*)d_in[2];
    const float* Wv = (const float*)d_in[3];
    const float* Wu = (const float*)d_in[4];
    const float* bu = (const float*)d_in[5];

    char* ws = (char*)d_ws;
    const size_t MB = 1ull << 20;
    u16* xb  = (u16*)(ws + 0);          // 4 MB  x as bf16 [4096][512]
    u16* Wqt = (u16*)(ws + 4 * MB);     // 3 x 4 MB: Wq^T,Wk^T,Wv^T bf16 [4096][512] contiguous
    u16* Wut = (u16*)(ws + 16 * MB);    // 4 MB  Wu^T bf16 [512][4096]
    u16* Qb  = (u16*)(ws + 20 * MB);    // 2 x 32 MB: Q,K [bh][t][d] (Q pre-scaled)
    u16* Kb  = (u16*)(ws + 52 * MB);
    u16* Vtb = (u16*)(ws + 116 * MB);   // 32 MB [bh][d][t] (written directly by gemm_qkv z=2)
    u16* Ob  = (u16*)(ws + 84 * MB);    // 32 MB [b*t][h*d]

    prep_kernel<<<4096, 256, 0, stream>>>(x, Wq, Wk, Wv, Wu, xb, Wqt, Wut);

    // 512^-0.5 * log2(e): softmax runs in base-2 (exp2f), fold conversion into Q scale
    const float s2 = 0.06375871593f;
    gemm_qkv<<<dim3(32, 32, 3), 256, 0, stream>>>(xb, Wqt, s2, Qb, Vtb);

    attn_kernel<<<256, 512, 0, stream>>>(Qb, Kb, Vtb, Ob);

    gemm_final<<<dim3(8, 32), 256, 0, stream>>>(Ob, Wut, bu, (float*)d_out, 4096);
}

// Round 14
// 443.764 us; speedup vs baseline: 1.1260x; 1.0298x over previous
//
#include <hip/hip_runtime.h>

typedef unsigned short u16;
typedef unsigned short ushort8 __attribute__((ext_vector_type(8)));
typedef unsigned short us4 __attribute__((ext_vector_type(4)));
typedef __bf16 bf16x8 __attribute__((ext_vector_type(8)));
typedef float f32x4 __attribute__((ext_vector_type(4)));

#define DEV static __device__ __forceinline__

// ---------- helpers ----------
DEV u16 f2bf(float f) {   // round-to-nearest-even f32 -> bf16
    unsigned int u = __builtin_bit_cast(unsigned int, f);
    u += 0x7FFFu + ((u >> 16) & 1u);
    return (u16)(u >> 16);
}

DEV f32x4 mfma16(ushort8 a, ushort8 b, f32x4 c) {
    return __builtin_amdgcn_mfma_f32_16x16x32_bf16((bf16x8)a, (bf16x8)b, c, 0, 0, 0);
}

DEV void gload_lds16(const void* g, void* l) {   // async global->LDS, dst = base + lane*16
    __builtin_amdgcn_global_load_lds(
        (const __attribute__((address_space(1))) void*)g,
        (__attribute__((address_space(3))) void*)l, 16, 0, 0);
}

// ---------- fused prep: x cvt + Wq/Wk/Wv transpose + Wu transpose (one launch) ----------
// flat grid 4096: [0,2048) x->bf16; [2048,3584) W{q,k,v}^T; [3584,4096) Wu^T.
__global__ void prep_kernel(const float* __restrict__ x,
                            const float* __restrict__ Wq, const float* __restrict__ Wk,
                            const float* __restrict__ Wv, const float* __restrict__ Wu,
                            u16* __restrict__ xb, u16* __restrict__ Wqt, u16* __restrict__ Wut) {
    __shared__ u16 tile[64][72];
    const int bid = blockIdx.x;

    if (bid < 2048) {                              // x fp32 -> bf16, vectorized
        int i = (bid * 256 + threadIdx.x) * 4;
        float4 f = *(const float4*)(x + i);
        us4 o;
        o.x = f2bf(f.x); o.y = f2bf(f.y); o.z = f2bf(f.z); o.w = f2bf(f.w);
        *(us4*)(xb + i) = o;
        return;
    }

    const float* in;
    u16* out;
    int R, C, c0, r0;
    if (bid < 3584) {                              // Wq/Wk/Wv [512][4096] -> ^T bf16
        int j = bid - 2048;
        int z = j >> 9, rem = j & 511;
        in = (z == 0) ? Wq : (z == 1) ? Wk : Wv;
        out = Wqt + (size_t)z * 2097152;           // 4 MB stride
        R = 512; C = 4096;
        c0 = (rem & 63) << 6; r0 = (rem >> 6) << 6;
    } else {                                       // Wu [4096][512] -> ^T bf16
        int k = bid - 3584;
        in = Wu; out = Wut;
        R = 4096; C = 512;
        c0 = (k & 7) << 6; r0 = (k >> 3) << 6;
    }
    int tx = threadIdx.x & 63, ty = threadIdx.x >> 6;
    for (int i = 0; i < 64; i += 4) {
        int r = i + ty;
        tile[r][tx] = f2bf(in[(size_t)(r0 + r) * C + c0 + tx]);
    }
    __syncthreads();
    for (int i = 0; i < 64; i += 4) {
        int r = i + ty;
        out[(size_t)(c0 + r) * R + r0 + tx] = tile[tx][r];
    }
}

// ---------- QKV GEMM (z-fused): C = xb @ W{q,k,v}t^T, 128x128 tile, BK=64, Kc=512 ----------
// XOR-swizzled 128B LDS rows (linear DMA dest + inverse-swizzled global source chunk +
// same-XOR read). K accumulation order matches BK=32 -> bit-identical output.
// z==2 (V) stores DIRECTLY TRANSPOSED to Vtb [bh][d][t]: packed 8B store.
__launch_bounds__(256, 3)
__global__ void gemm_qkv(const u16* __restrict__ A, const u16* __restrict__ Btbase,
                         float s2, u16* __restrict__ outbase, u16* __restrict__ vtb) {
    __shared__ u16 Asub[128 * 64];   // 16 KB, XOR-swizzled rows of 128 B
    __shared__ u16 Bsub[128 * 64];   // 16 KB
    const int Kc = 512;
    const u16* Bt = Btbase + (size_t)blockIdx.z * 2097152;     // 4 MB stride
    u16* out = outbase + (size_t)blockIdx.z * 16777216;        // 32 MB stride (z=0,1)
    const float scale = (blockIdx.z == 0) ? s2 : 1.0f;

    const int tid = threadIdx.x, lane = tid & 63, wv = tid >> 6;
    const int bm = blockIdx.y << 7, bn = blockIdx.x << 7;
    const int wr = (wv >> 1) << 6, wc = (wv & 1) << 6;
    const int lr = lane & 15, hi = lane >> 4;

    f32x4 acc[4][4] = {};

    // staging: wave wv owns rows [wv*32, wv*32+32) of A and B; 4 gloads each (1KB = 8 rows).
    const int srow = lane >> 3;
    const int schunk = ((lane & 7) ^ srow) * 8;    // element offset of this lane's 16B chunk
    const u16* Ag[4];
    const u16* Bg[4];
#pragma unroll
    for (int g = 0; g < 4; ++g) {
        int row = wv * 32 + g * 8 + srow;
        Ag[g] = A + (size_t)(bm + row) * Kc + schunk;
        Bg[g] = Bt + (size_t)(bn + row) * Kc + schunk;
    }

    for (int kk = 0; kk < Kc; kk += 64) {
        __syncthreads();
#pragma unroll
        for (int g = 0; g < 4; ++g) {
            gload_lds16(Ag[g] + kk, &Asub[(wv * 32 + g * 8) * 64]);
            gload_lds16(Bg[g] + kk, &Bsub[(wv * 32 + g * 8) * 64]);
        }
        __syncthreads();

#pragma unroll
        for (int kh = 0; kh < 2; ++kh) {           // two K=32 halves, same accumulation order
            const int coff = (kh * 64 + hi * 16) ^ ((lr & 7) << 4);   // swizzled byte-in-row
            ushort8 a[4], b[4];
#pragma unroll
            for (int m = 0; m < 4; ++m)
                a[m] = *(const ushort8*)((const char*)Asub + (wr + m * 16 + lr) * 128 + coff);
#pragma unroll
            for (int n = 0; n < 4; ++n)
                b[n] = *(const ushort8*)((const char*)Bsub + (wc + n * 16 + lr) * 128 + coff);
#pragma unroll
            for (int m = 0; m < 4; ++m)
#pragma unroll
                for (int n = 0; n < 4; ++n)
                    acc[m][n] = mfma16(a[m], b[n], acc[m][n]);
        }
    }

    if (blockIdx.z == 2) {
        // V: packed-transposed store to Vtb[bh][d][t]
#pragma unroll
        for (int m = 0; m < 4; ++m)
#pragma unroll
            for (int n = 0; n < 4; ++n) {
                int row0v = bm + wr + m * 16 + hi * 4;     // token = b*2048 + t0 (t0 % 4 == 0)
                int col   = bn + wc + n * 16 + lr;         // h*512 + d
                int b = row0v >> 11, t0 = row0v & 2047;
                int h = col >> 9, d = col & 511;
                us4 pk;
#pragma unroll
                for (int r = 0; r < 4; ++r) pk[r] = f2bf(acc[m][n][r]);
                *(us4*)&vtb[(((size_t)(b * 8 + h) * 512 + d) << 11) + t0] = pk;
            }
    } else {
#pragma unroll
        for (int m = 0; m < 4; ++m)
#pragma unroll
            for (int n = 0; n < 4; ++n)
#pragma unroll
                for (int r = 0; r < 4; ++r) {
                    int row = bm + wr + m * 16 + hi * 4 + r;   // token index b*2048+t
                    int col = bn + wc + n * 16 + lr;           // h*512+d
                    float v = acc[m][n][r] * scale;
                    size_t dst = ((size_t)((row >> 11) * 8 + (col >> 9)) * 2048 + (row & 2047)) * 512
                                 + (col & 511);
                    out[dst] = f2bf(v);
                }
    }
}

// ---------- final GEMM: out[4096][512] = Ob[4096][4096] @ Wut[512][4096]^T + bu ----------
// BM=64, BN=64 -> grid (8,64) = 512 blocks = 2 blocks/CU = 2 waves/SIMD (was 1 —
// the only kernel at 1 wave/SIMD; K=4096 serial chain had zero TLP cover).
// 4 waves in 2x2; wave = 32x32, acc[2][2]. BK=64 XOR-swizzled staging (16 segs,
// 4/wave). K order unchanged -> bit-identical output.
__launch_bounds__(256, 4)
__global__ void gemm_final(const u16* __restrict__ A, const u16* __restrict__ Bt,
                           const float* __restrict__ bias, float* __restrict__ out, int Kc) {
    __shared__ u16 Asub[64 * 64];    // 8 KB
    __shared__ u16 Bsub[64 * 64];    // 8 KB
    const int tid = threadIdx.x, lane = tid & 63, wv = tid >> 6;
    const int bm = blockIdx.y << 6, bn = blockIdx.x << 6;
    const int wr = (wv >> 1) << 5, wc = (wv & 1) << 5;
    const int lr = lane & 15, hi = lane >> 4;

    f32x4 acc[2][2] = {};

    const int srow = lane >> 3;
    const int schunk = ((lane & 7) ^ srow) * 8;
    const u16* gsrc[4];
    u16* ldst[4];
#pragma unroll
    for (int j = 0; j < 4; ++j) {
        int g = wv * 4 + j;
        if (g < 8) {                       // A segs: rows g*8 + srow
            int row = g * 8 + srow;
            gsrc[j] = A + (size_t)(bm + row) * Kc + schunk;
            ldst[j] = &Asub[g * 8 * 64];
        } else {                           // B segs: rows (g-8)*8 + srow
            int row = (g - 8) * 8 + srow;
            gsrc[j] = Bt + (size_t)(bn + row) * Kc + schunk;
            ldst[j] = &Bsub[(g - 8) * 8 * 64];
        }
    }

    for (int kk = 0; kk < Kc; kk += 64) {
        __syncthreads();
#pragma unroll
        for (int j = 0; j < 4; ++j) gload_lds16(gsrc[j] + kk, ldst[j]);
        __syncthreads();

#pragma unroll
        for (int kh = 0; kh < 2; ++kh) {
            const int coff = (kh * 64 + hi * 16) ^ ((lr & 7) << 4);
            ushort8 a[2], b[2];
#pragma unroll
            for (int m = 0; m < 2; ++m)
                a[m] = *(const ushort8*)((const char*)Asub + (wr + m * 16 + lr) * 128 + coff);
#pragma unroll
            for (int n = 0; n < 2; ++n)
                b[n] = *(const ushort8*)((const char*)Bsub + (wc + n * 16 + lr) * 128 + coff);
#pragma unroll
            for (int m = 0; m < 2; ++m)
#pragma unroll
                for (int n = 0; n < 2; ++n)
                    acc[m][n] = mfma16(a[m], b[n], acc[m][n]);
        }
    }

#pragma unroll
    for (int m = 0; m < 2; ++m)
#pragma unroll
        for (int n = 0; n < 2; ++n)
#pragma unroll
            for (int r = 0; r < 4; ++r) {
                int row = bm + wr + m * 16 + hi * 4 + r;
                int col = bn + wc + n * 16 + lr;
                out[(size_t)row * 512 + col] = acc[m][n][r] + bias[col];
            }
}

// ---------- flash attention (v7 attn, FROZEN — verified local optimum) ----------
// T15 att[2] pipelining: iter t issues S(t) MFMAs, runs softmax(t-1) in their shadow,
// one barrier, then PV(t-1). K dbuf via global_load_lds (pre-swizzled source).
// DO NOT move V loads (v3 pre-barrier, v8 batch-hoist, v11 dual-stream interleave
// all regressed); inline per-nf loads let the compiler roll load(nf+1) under MFMAs(nf).
__launch_bounds__(512, 2)
__global__ void attn_kernel(const u16* __restrict__ Q, const u16* __restrict__ K,
                            const u16* __restrict__ Vt, u16* __restrict__ O) {
    __shared__ u16 Klds[2][32 * 512];            // 2 x 32KB, XOR-swizzled rows
    __shared__ u16 Plds[2][128 * 40];            // [q][32 keys + 8 pad]
    __shared__ __align__(16) float red[2][128];  // per-row alpha
    __shared__ __align__(16) float lred[128];    // final l
    __shared__ int rflag[2][8];                  // per-wave "some row rescaled"

    const int tid = threadIdx.x, lane = tid & 63, wv = tid >> 6;
    const int lr = lane & 15, hi = lane >> 4;
    const int qh = wv >> 2, ds = wv & 3;         // PV decomposition

    // XCD-chunked bijective swizzle: 256 blocks = 8 XCDs x 32; 2 bh per XCD chunk
    const int flat = blockIdx.x;
    const int nid = (flat & 7) * 32 + (flat >> 3);
    const int bh = nid >> 4;
    const int q0 = (nid & 15) << 7;

    // Q fragments (B-operand: col=lane&15 -> q-row wv*16+lr, k-slice hi*8..+8)
    ushort8 qf[16];
    {
        const char* Qg = (const char*)(Q + ((size_t)bh * 2048 + q0 + wv * 16 + lr) * 512) + hi * 16;
#pragma unroll
        for (int ks = 0; ks < 16; ++ks) qf[ks] = *(const ushort8*)(Qg + ks * 64);
    }

    f32x4 acc[4][8] = {};   // [q 16-block within 64-row half][d 16-frag within 128-wide slice]
    float mrun = -1e30f, lrun = 0.f;   // per-lane, q = wv*16+lr (replicated over hi), base-2

    const char* Kg = (const char*)(K + (size_t)bh * 2048 * 512);
    const char* Vg = (const char*)(Vt + (size_t)bh * 512 * 2048);

    // S-phase: 32 MFMAs into two chains (keys lr / lr+16), zero-started
    auto s_phase = [&](const char* Kb, f32x4& s0, f32x4& s1) {
        s0 = (f32x4){0.f, 0.f, 0.f, 0.f};
        s1 = (f32x4){0.f, 0.f, 0.f, 0.f};
#pragma unroll
        for (int ks = 0; ks < 16; ++ks) {
            int swz = (ks * 64 + hi * 16) ^ ((lr & 7) << 4);
            ushort8 kf0 = *(const ushort8*)(Kb + lr * 1024 + swz);
            ushort8 kf1 = *(const ushort8*)(Kb + (lr + 16) * 1024 + swz);
            s0 = mfma16(kf0, qf[ks], s0);
            s1 = mfma16(kf1, qf[ks], s1);
        }
    };

    // softmax on a finished S pair; writes P/alpha/flag into slot pcb
    auto softmax_store = [&](const f32x4& s0, const f32x4& s1, int pcb) {
        float mx = fmaxf(fmaxf(fmaxf(s0[0], s0[1]), fmaxf(s0[2], s0[3])),
                         fmaxf(fmaxf(s1[0], s1[1]), fmaxf(s1[2], s1[3])));
        mx = fmaxf(mx, __shfl_xor(mx, 16));
        mx = fmaxf(mx, __shfl_xor(mx, 32));
        float a = 1.0f;
        bool upd = false;
        if (mx > mrun + 11.5f) { a = exp2f(mrun - mx); mrun = mx; upd = true; }   // defer-max
        float p[8];
#pragma unroll
        for (int r = 0; r < 4; ++r) {
            p[r]     = exp2f(s0[r] - mrun);
            p[4 + r] = exp2f(s1[r] - mrun);
        }
        float ps = ((p[0] + p[1]) + (p[2] + p[3])) + ((p[4] + p[5]) + (p[6] + p[7]));
        ps += __shfl_xor(ps, 16);
        ps += __shfl_xor(ps, 32);
        lrun = lrun * a + ps;

        const int qr = wv * 16 + lr;
        char* Pb = (char*)&Plds[pcb][0] + qr * 80;
        uint2 w01, w23;
        w01.x = (unsigned)f2bf(p[0]) | ((unsigned)f2bf(p[1]) << 16);
        w01.y = (unsigned)f2bf(p[2]) | ((unsigned)f2bf(p[3]) << 16);
        w23.x = (unsigned)f2bf(p[4]) | ((unsigned)f2bf(p[5]) << 16);
        w23.y = (unsigned)f2bf(p[6]) | ((unsigned)f2bf(p[7]) << 16);
        *(uint2*)(Pb + hi * 8) = w01;
        *(uint2*)(Pb + 32 + hi * 8) = w23;
        if (hi == 0) red[pcb][qr] = a;
        if (lane == 0) rflag[pcb][wv] = __any(upd) ? 1 : 0;
    };

    // rescale (defer-max gated) + PV for tile whose P sits in slot pcb, V tile at key ktv
    auto pv_phase = [&](int pcb, int ktv) {
        int anyupd = rflag[pcb][0] | rflag[pcb][1] | rflag[pcb][2] | rflag[pcb][3]
                   | rflag[pcb][4] | rflag[pcb][5] | rflag[pcb][6] | rflag[pcb][7];
        if (anyupd) {
#pragma unroll
            for (int mf = 0; mf < 4; ++mf) {
                f32x4 a4 = *(const f32x4*)&red[pcb][qh * 64 + mf * 16 + hi * 4];
#pragma unroll
                for (int nf = 0; nf < 8; ++nf)
#pragma unroll
                    for (int r = 0; r < 4; ++r) acc[mf][nf][r] *= a4[r];
            }
        }
        ushort8 pf[4];
#pragma unroll
        for (int mf = 0; mf < 4; ++mf)
            pf[mf] = *(const ushort8*)((const char*)&Plds[pcb][0]
                                       + (qh * 64 + mf * 16 + lr) * 80 + hi * 16);
        __builtin_amdgcn_s_setprio(1);
#pragma unroll
        for (int nf = 0; nf < 8; ++nf) {
            int d = ds * 128 + nf * 16 + lr;
            ushort8 vf = *(const ushort8*)(Vg + (size_t)d * 4096 + (size_t)ktv * 2 + hi * 16);
#pragma unroll
            for (int mf = 0; mf < 4; ++mf) acc[mf][nf] = mfma16(pf[mf], vf, acc[mf][nf]);
        }
        __builtin_amdgcn_s_setprio(0);
    };

    auto prefetch_k = [&](int tt) {   // stage K(tt) into buf tt&1
        const char* Kgt = Kg + (size_t)tt * 32 * 1024;
#pragma unroll
        for (int r4 = 0; r4 < 4; ++r4) {
            int r = wv * 4 + r4;
            gload_lds16(Kgt + (size_t)r * 1024 + ((lane ^ (r & 7)) << 4),
                        &Klds[tt & 1][(size_t)r * 512]);
        }
    };

    f32x4 s0c, s1c, s0p, s1p;

    // prologue: K(0) -> buf0
    prefetch_k(0);
    __syncthreads();                       // K0 ready

    // peeled iter 0: prefetch K(1), S(0); no softmax/PV yet
    prefetch_k(1);
    s_phase((const char*)&Klds[0][0], s0c, s1c);
    __syncthreads();                       // K1 DMA drained; S(0) reads of buf0 done

    for (int t = 1; t < 64; ++t) {
        if (t + 1 < 64) prefetch_k(t + 1);       // -> buf (t+1)&1 (= buf read by S(t-1), done)

        s0p = s0c; s1p = s1c;                     // retire S(t-1) results
        s_phase((const char*)&Klds[t & 1][0], s0c, s1c);   // S(t) in flight...
        softmax_store(s0p, s1p, (t - 1) & 1);     // ...while softmax(t-1) runs on VALU

        __syncthreads();   // P(t-1)/alpha visible; K(t+1) drained; buf[t&1] reads done

        pv_phase((t - 1) & 1, (t - 1) << 5);
    }

    // epilogue: tile 63
    softmax_store(s0c, s1c, 1);
    __syncthreads();
    pv_phase(1, 63 << 5);

    // final l for all 128 rows -> LDS
    if (hi == 0) lred[wv * 16 + lr] = lrun;
    __syncthreads();

    const int b = bh >> 3, h = bh & 7;
#pragma unroll
    for (int mf = 0; mf < 4; ++mf) {
        f32x4 lv = *(const f32x4*)&lred[qh * 64 + mf * 16 + hi * 4];
        f32x4 inv;
#pragma unroll
        for (int r = 0; r < 4; ++r) inv[r] = 1.0f / lv[r];
#pragma unroll
        for (int nf = 0; nf < 8; ++nf) {
            int d = ds * 128 + nf * 16 + lr;
#pragma unroll
            for (int r = 0; r < 4; ++r) {
                int t = q0 + qh * 64 + mf * 16 + hi * 4 + r;
                O[((size_t)(b * 2048 + t)) * 4096 + h * 512 + d] = f2bf(acc[mf][nf][r] * inv[r]);
            }
        }
    }
}

// ---------- host ----------
extern "C" void kernel_launch(void* const* d_in, const int* in_sizes, int n_in,
                              void* d_out, int out_size, void* d_ws, size_t ws_size,
                              hipStream_t stream) {
    const float* x  = (const float*)d_in[0];
    const float* Wq = (const float*)d_in[1];
    const float* Wk = (const float*)d_in[2];
    const float* Wv = (const float*)d_in[3];
    const float* Wu = (const float*)d_in[4];
    const float* bu = (const float*)d_in[5];

    char* ws = (char*)d_ws;
    const size_t MB = 1ull << 20;
    u16* xb  = (u16*)(ws + 0);          // 4 MB  x as bf16 [4096][512]
    u16* Wqt = (u16*)(ws + 4 * MB);     // 3 x 4 MB: Wq^T,Wk^T,Wv^T bf16 [4096][512] contiguous
    u16* Wut = (u16*)(ws + 16 * MB);    // 4 MB  Wu^T bf16 [512][4096]
    u16* Qb  = (u16*)(ws + 20 * MB);    // 2 x 32 MB: Q,K [bh][t][d] (Q pre-scaled)
    u16* Kb  = (u16*)(ws + 52 * MB);
    u16* Vtb = (u16*)(ws + 116 * MB);   // 32 MB [bh][d][t] (written directly by gemm_qkv z=2)
    u16* Ob  = (u16*)(ws + 84 * MB);    // 32 MB [b*t][h*d]

    prep_kernel<<<4096, 256, 0, stream>>>(x, Wq, Wk, Wv, Wu, xb, Wqt, Wut);

    // 512^-0.5 * log2(e): softmax runs in base-2 (exp2f), fold conversion into Q scale
    const float s2 = 0.06375871593f;
    gemm_qkv<<<dim3(32, 32, 3), 256, 0, stream>>>(xb, Wqt, s2, Qb, Vtb);

    attn_kernel<<<256, 512, 0, stream>>>(Qb, Kb, Vtb, Ob);

    gemm_final<<<dim3(8, 64), 256, 0, stream>>>(Ob, Wut, bu, (float*)d_out, 4096);
}

// Round 15
// 438.777 us; speedup vs baseline: 1.1388x; 1.0114x over previous
//
#include <hip/hip_runtime.h>

typedef unsigned short u16;
typedef unsigned short ushort8 __attribute__((ext_vector_type(8)));
typedef unsigned short us4 __attribute__((ext_vector_type(4)));
typedef __bf16 bf16x8 __attribute__((ext_vector_type(8)));
typedef float f32x4 __attribute__((ext_vector_type(4)));

#define DEV static __device__ __forceinline__

// ---------- helpers ----------
DEV u16 f2bf(float f) {   // round-to-nearest-even f32 -> bf16
    unsigned int u = __builtin_bit_cast(unsigned int, f);
    u += 0x7FFFu + ((u >> 16) & 1u);
    return (u16)(u >> 16);
}

DEV f32x4 mfma16(ushort8 a, ushort8 b, f32x4 c) {
    return __builtin_amdgcn_mfma_f32_16x16x32_bf16((bf16x8)a, (bf16x8)b, c, 0, 0, 0);
}

DEV void gload_lds16(const void* g, void* l) {   // async global->LDS, dst = base + lane*16
    __builtin_amdgcn_global_load_lds(
        (const __attribute__((address_space(1))) void*)g,
        (__attribute__((address_space(3))) void*)l, 16, 0, 0);
}

// ---------- fused prep: x cvt + Wq/Wk/Wv transpose + Wu transpose (one launch) ----------
// flat grid 4096: [0,2048) x->bf16; [2048,3584) W{q,k,v}^T; [3584,4096) Wu^T.
__global__ void prep_kernel(const float* __restrict__ x,
                            const float* __restrict__ Wq, const float* __restrict__ Wk,
                            const float* __restrict__ Wv, const float* __restrict__ Wu,
                            u16* __restrict__ xb, u16* __restrict__ Wqt, u16* __restrict__ Wut) {
    __shared__ u16 tile[64][72];
    const int bid = blockIdx.x;

    if (bid < 2048) {                              // x fp32 -> bf16, vectorized
        int i = (bid * 256 + threadIdx.x) * 4;
        float4 f = *(const float4*)(x + i);
        us4 o;
        o.x = f2bf(f.x); o.y = f2bf(f.y); o.z = f2bf(f.z); o.w = f2bf(f.w);
        *(us4*)(xb + i) = o;
        return;
    }

    const float* in;
    u16* out;
    int R, C, c0, r0;
    if (bid < 3584) {                              // Wq/Wk/Wv [512][4096] -> ^T bf16
        int j = bid - 2048;
        int z = j >> 9, rem = j & 511;
        in = (z == 0) ? Wq : (z == 1) ? Wk : Wv;
        out = Wqt + (size_t)z * 2097152;           // 4 MB stride
        R = 512; C = 4096;
        c0 = (rem & 63) << 6; r0 = (rem >> 6) << 6;
    } else {                                       // Wu [4096][512] -> ^T bf16
        int k = bid - 3584;
        in = Wu; out = Wut;
        R = 4096; C = 512;
        c0 = (k & 7) << 6; r0 = (k >> 3) << 6;
    }
    int tx = threadIdx.x & 63, ty = threadIdx.x >> 6;
    for (int i = 0; i < 64; i += 4) {
        int r = i + ty;
        tile[r][tx] = f2bf(in[(size_t)(r0 + r) * C + c0 + tx]);
    }
    __syncthreads();
    for (int i = 0; i < 64; i += 4) {
        int r = i + ty;
        out[(size_t)(c0 + r) * R + r0 + tx] = tile[tx][r];
    }
}

// ---------- QKV GEMM (z-fused): C = xb @ W{q,k,v}t^T, 128x128 tile, BK=64, Kc=512 ----------
// XOR-swizzled 128B LDS rows (linear DMA dest + inverse-swizzled global source chunk +
// same-XOR read). K accumulation order matches BK=32 -> bit-identical output.
// z==2 (V) stores DIRECTLY TRANSPOSED to Vtb [bh][d][t]: packed 8B store.
__launch_bounds__(256, 3)
__global__ void gemm_qkv(const u16* __restrict__ A, const u16* __restrict__ Btbase,
                         float s2, u16* __restrict__ outbase, u16* __restrict__ vtb) {
    __shared__ u16 Asub[128 * 64];   // 16 KB, XOR-swizzled rows of 128 B
    __shared__ u16 Bsub[128 * 64];   // 16 KB
    const int Kc = 512;
    const u16* Bt = Btbase + (size_t)blockIdx.z * 2097152;     // 4 MB stride
    u16* out = outbase + (size_t)blockIdx.z * 16777216;        // 32 MB stride (z=0,1)
    const float scale = (blockIdx.z == 0) ? s2 : 1.0f;

    const int tid = threadIdx.x, lane = tid & 63, wv = tid >> 6;
    const int bm = blockIdx.y << 7, bn = blockIdx.x << 7;
    const int wr = (wv >> 1) << 6, wc = (wv & 1) << 6;
    const int lr = lane & 15, hi = lane >> 4;

    f32x4 acc[4][4] = {};

    // staging: wave wv owns rows [wv*32, wv*32+32) of A and B; 4 gloads each (1KB = 8 rows).
    const int srow = lane >> 3;
    const int schunk = ((lane & 7) ^ srow) * 8;    // element offset of this lane's 16B chunk
    const u16* Ag[4];
    const u16* Bg[4];
#pragma unroll
    for (int g = 0; g < 4; ++g) {
        int row = wv * 32 + g * 8 + srow;
        Ag[g] = A + (size_t)(bm + row) * Kc + schunk;
        Bg[g] = Bt + (size_t)(bn + row) * Kc + schunk;
    }

    for (int kk = 0; kk < Kc; kk += 64) {
        __syncthreads();
#pragma unroll
        for (int g = 0; g < 4; ++g) {
            gload_lds16(Ag[g] + kk, &Asub[(wv * 32 + g * 8) * 64]);
            gload_lds16(Bg[g] + kk, &Bsub[(wv * 32 + g * 8) * 64]);
        }
        __syncthreads();

#pragma unroll
        for (int kh = 0; kh < 2; ++kh) {           // two K=32 halves, same accumulation order
            const int coff = (kh * 64 + hi * 16) ^ ((lr & 7) << 4);   // swizzled byte-in-row
            ushort8 a[4], b[4];
#pragma unroll
            for (int m = 0; m < 4; ++m)
                a[m] = *(const ushort8*)((const char*)Asub + (wr + m * 16 + lr) * 128 + coff);
#pragma unroll
            for (int n = 0; n < 4; ++n)
                b[n] = *(const ushort8*)((const char*)Bsub + (wc + n * 16 + lr) * 128 + coff);
#pragma unroll
            for (int m = 0; m < 4; ++m)
#pragma unroll
                for (int n = 0; n < 4; ++n)
                    acc[m][n] = mfma16(a[m], b[n], acc[m][n]);
        }
    }

    if (blockIdx.z == 2) {
        // V: packed-transposed store to Vtb[bh][d][t]
#pragma unroll
        for (int m = 0; m < 4; ++m)
#pragma unroll
            for (int n = 0; n < 4; ++n) {
                int row0v = bm + wr + m * 16 + hi * 4;     // token = b*2048 + t0 (t0 % 4 == 0)
                int col   = bn + wc + n * 16 + lr;         // h*512 + d
                int b = row0v >> 11, t0 = row0v & 2047;
                int h = col >> 9, d = col & 511;
                us4 pk;
#pragma unroll
                for (int r = 0; r < 4; ++r) pk[r] = f2bf(acc[m][n][r]);
                *(us4*)&vtb[(((size_t)(b * 8 + h) * 512 + d) << 11) + t0] = pk;
            }
    } else {
#pragma unroll
        for (int m = 0; m < 4; ++m)
#pragma unroll
            for (int n = 0; n < 4; ++n)
#pragma unroll
                for (int r = 0; r < 4; ++r) {
                    int row = bm + wr + m * 16 + hi * 4 + r;   // token index b*2048+t
                    int col = bn + wc + n * 16 + lr;           // h*512+d
                    float v = acc[m][n][r] * scale;
                    size_t dst = ((size_t)((row >> 11) * 8 + (col >> 9)) * 2048 + (row & 2047)) * 512
                                 + (col & 511);
                    out[dst] = f2bf(v);
                }
    }
}

// ---------- final GEMM: out[4096][512] = Ob[4096][4096] @ Wut[512][4096]^T + bu ----------
// BM=64, BN=32 -> grid (16,64) = 1024 blocks = 4 blocks/CU = 4 waves/SIMD (r14's
// 1->2 doubling gained 13 us on this latency-bound K=4096 chain; repeat 2->4).
// 4 waves in 2x2; wave = 32x16, acc[2][1]. BK=64 XOR-swizzled staging (12 segs,
// 3/wave: A 8, B 4). K order unchanged -> bit-identical output.
__launch_bounds__(256, 4)
__global__ void gemm_final(const u16* __restrict__ A, const u16* __restrict__ Bt,
                           const float* __restrict__ bias, float* __restrict__ out, int Kc) {
    __shared__ u16 Asub[64 * 64];    // 8 KB
    __shared__ u16 Bsub[32 * 64];    // 4 KB
    const int tid = threadIdx.x, lane = tid & 63, wv = tid >> 6;
    const int bm = blockIdx.y << 6, bn = blockIdx.x << 5;
    const int wr = (wv >> 1) << 5, wc = (wv & 1) << 4;
    const int lr = lane & 15, hi = lane >> 4;

    f32x4 acc[2][1] = {};

    const int srow = lane >> 3;
    const int schunk = ((lane & 7) ^ srow) * 8;
    const u16* gsrc[3];
    u16* ldst[3];
#pragma unroll
    for (int j = 0; j < 3; ++j) {
        int g = wv * 3 + j;
        if (g < 8) {                       // A segs: rows g*8 + srow (tile rows 0..63)
            int row = g * 8 + srow;
            gsrc[j] = A + (size_t)(bm + row) * Kc + schunk;
            ldst[j] = &Asub[g * 8 * 64];
        } else {                           // B segs: rows (g-8)*8 + srow (tile rows 0..31)
            int row = (g - 8) * 8 + srow;
            gsrc[j] = Bt + (size_t)(bn + row) * Kc + schunk;
            ldst[j] = &Bsub[(g - 8) * 8 * 64];
        }
    }

    for (int kk = 0; kk < Kc; kk += 64) {
        __syncthreads();
#pragma unroll
        for (int j = 0; j < 3; ++j) gload_lds16(gsrc[j] + kk, ldst[j]);
        __syncthreads();

#pragma unroll
        for (int kh = 0; kh < 2; ++kh) {
            const int coff = (kh * 64 + hi * 16) ^ ((lr & 7) << 4);
            ushort8 a[2], b;
#pragma unroll
            for (int m = 0; m < 2; ++m)
                a[m] = *(const ushort8*)((const char*)Asub + (wr + m * 16 + lr) * 128 + coff);
            b = *(const ushort8*)((const char*)Bsub + (wc + lr) * 128 + coff);
#pragma unroll
            for (int m = 0; m < 2; ++m)
                acc[m][0] = mfma16(a[m], b, acc[m][0]);
        }
    }

#pragma unroll
    for (int m = 0; m < 2; ++m)
#pragma unroll
        for (int r = 0; r < 4; ++r) {
            int row = bm + wr + m * 16 + hi * 4 + r;
            int col = bn + wc + lr;
            out[(size_t)row * 512 + col] = acc[m][0][r] + bias[col];
        }
}

// ---------- flash attention (v7 attn, FROZEN — verified local optimum) ----------
// T15 att[2] pipelining: iter t issues S(t) MFMAs, runs softmax(t-1) in their shadow,
// one barrier, then PV(t-1). K dbuf via global_load_lds (pre-swizzled source).
// DO NOT move V loads (v3 pre-barrier, v8 batch-hoist, v11 dual-stream interleave
// all regressed); inline per-nf loads let the compiler roll load(nf+1) under MFMAs(nf).
// Occupancy is register-pinned (acc 128 AGPR + qf 64 + temps -> 2 waves/SIMD on the
// 512-reg/SIMD pool); every decomposition escape audited infeasible at D=512.
__launch_bounds__(512, 2)
__global__ void attn_kernel(const u16* __restrict__ Q, const u16* __restrict__ K,
                            const u16* __restrict__ Vt, u16* __restrict__ O) {
    __shared__ u16 Klds[2][32 * 512];            // 2 x 32KB, XOR-swizzled rows
    __shared__ u16 Plds[2][128 * 40];            // [q][32 keys + 8 pad]
    __shared__ __align__(16) float red[2][128];  // per-row alpha
    __shared__ __align__(16) float lred[128];    // final l
    __shared__ int rflag[2][8];                  // per-wave "some row rescaled"

    const int tid = threadIdx.x, lane = tid & 63, wv = tid >> 6;
    const int lr = lane & 15, hi = lane >> 4;
    const int qh = wv >> 2, ds = wv & 3;         // PV decomposition

    // XCD-chunked bijective swizzle: 256 blocks = 8 XCDs x 32; 2 bh per XCD chunk
    const int flat = blockIdx.x;
    const int nid = (flat & 7) * 32 + (flat >> 3);
    const int bh = nid >> 4;
    const int q0 = (nid & 15) << 7;

    // Q fragments (B-operand: col=lane&15 -> q-row wv*16+lr, k-slice hi*8..+8)
    ushort8 qf[16];
    {
        const char* Qg = (const char*)(Q + ((size_t)bh * 2048 + q0 + wv * 16 + lr) * 512) + hi * 16;
#pragma unroll
        for (int ks = 0; ks < 16; ++ks) qf[ks] = *(const ushort8*)(Qg + ks * 64);
    }

    f32x4 acc[4][8] = {};   // [q 16-block within 64-row half][d 16-frag within 128-wide slice]
    float mrun = -1e30f, lrun = 0.f;   // per-lane, q = wv*16+lr (replicated over hi), base-2

    const char* Kg = (const char*)(K + (size_t)bh * 2048 * 512);
    const char* Vg = (const char*)(Vt + (size_t)bh * 512 * 2048);

    // S-phase: 32 MFMAs into two chains (keys lr / lr+16), zero-started
    auto s_phase = [&](const char* Kb, f32x4& s0, f32x4& s1) {
        s0 = (f32x4){0.f, 0.f, 0.f, 0.f};
        s1 = (f32x4){0.f, 0.f, 0.f, 0.f};
#pragma unroll
        for (int ks = 0; ks < 16; ++ks) {
            int swz = (ks * 64 + hi * 16) ^ ((lr & 7) << 4);
            ushort8 kf0 = *(const ushort8*)(Kb + lr * 1024 + swz);
            ushort8 kf1 = *(const ushort8*)(Kb + (lr + 16) * 1024 + swz);
            s0 = mfma16(kf0, qf[ks], s0);
            s1 = mfma16(kf1, qf[ks], s1);
        }
    };

    // softmax on a finished S pair; writes P/alpha/flag into slot pcb
    auto softmax_store = [&](const f32x4& s0, const f32x4& s1, int pcb) {
        float mx = fmaxf(fmaxf(fmaxf(s0[0], s0[1]), fmaxf(s0[2], s0[3])),
                         fmaxf(fmaxf(s1[0], s1[1]), fmaxf(s1[2], s1[3])));
        mx = fmaxf(mx, __shfl_xor(mx, 16));
        mx = fmaxf(mx, __shfl_xor(mx, 32));
        float a = 1.0f;
        bool upd = false;
        if (mx > mrun + 11.5f) { a = exp2f(mrun - mx); mrun = mx; upd = true; }   // defer-max
        float p[8];
#pragma unroll
        for (int r = 0; r < 4; ++r) {
            p[r]     = exp2f(s0[r] - mrun);
            p[4 + r] = exp2f(s1[r] - mrun);
        }
        float ps = ((p[0] + p[1]) + (p[2] + p[3])) + ((p[4] + p[5]) + (p[6] + p[7]));
        ps += __shfl_xor(ps, 16);
        ps += __shfl_xor(ps, 32);
        lrun = lrun * a + ps;

        const int qr = wv * 16 + lr;
        char* Pb = (char*)&Plds[pcb][0] + qr * 80;
        uint2 w01, w23;
        w01.x = (unsigned)f2bf(p[0]) | ((unsigned)f2bf(p[1]) << 16);
        w01.y = (unsigned)f2bf(p[2]) | ((unsigned)f2bf(p[3]) << 16);
        w23.x = (unsigned)f2bf(p[4]) | ((unsigned)f2bf(p[5]) << 16);
        w23.y = (unsigned)f2bf(p[6]) | ((unsigned)f2bf(p[7]) << 16);
        *(uint2*)(Pb + hi * 8) = w01;
        *(uint2*)(Pb + 32 + hi * 8) = w23;
        if (hi == 0) red[pcb][qr] = a;
        if (lane == 0) rflag[pcb][wv] = __any(upd) ? 1 : 0;
    };

    // rescale (defer-max gated) + PV for tile whose P sits in slot pcb, V tile at key ktv
    auto pv_phase = [&](int pcb, int ktv) {
        int anyupd = rflag[pcb][0] | rflag[pcb][1] | rflag[pcb][2] | rflag[pcb][3]
                   | rflag[pcb][4] | rflag[pcb][5] | rflag[pcb][6] | rflag[pcb][7];
        if (anyupd) {
#pragma unroll
            for (int mf = 0; mf < 4; ++mf) {
                f32x4 a4 = *(const f32x4*)&red[pcb][qh * 64 + mf * 16 + hi * 4];
#pragma unroll
                for (int nf = 0; nf < 8; ++nf)
#pragma unroll
                    for (int r = 0; r < 4; ++r) acc[mf][nf][r] *= a4[r];
            }
        }
        ushort8 pf[4];
#pragma unroll
        for (int mf = 0; mf < 4; ++mf)
            pf[mf] = *(const ushort8*)((const char*)&Plds[pcb][0]
                                       + (qh * 64 + mf * 16 + lr) * 80 + hi * 16);
        __builtin_amdgcn_s_setprio(1);
#pragma unroll
        for (int nf = 0; nf < 8; ++nf) {
            int d = ds * 128 + nf * 16 + lr;
            ushort8 vf = *(const ushort8*)(Vg + (size_t)d * 4096 + (size_t)ktv * 2 + hi * 16);
#pragma unroll
            for (int mf = 0; mf < 4; ++mf) acc[mf][nf] = mfma16(pf[mf], vf, acc[mf][nf]);
        }
        __builtin_amdgcn_s_setprio(0);
    };

    auto prefetch_k = [&](int tt) {   // stage K(tt) into buf tt&1
        const char* Kgt = Kg + (size_t)tt * 32 * 1024;
#pragma unroll
        for (int r4 = 0; r4 < 4; ++r4) {
            int r = wv * 4 + r4;
            gload_lds16(Kgt + (size_t)r * 1024 + ((lane ^ (r & 7)) << 4),
                        &Klds[tt & 1][(size_t)r * 512]);
        }
    };

    f32x4 s0c, s1c, s0p, s1p;

    // prologue: K(0) -> buf0
    prefetch_k(0);
    __syncthreads();                       // K0 ready

    // peeled iter 0: prefetch K(1), S(0); no softmax/PV yet
    prefetch_k(1);
    s_phase((const char*)&Klds[0][0], s0c, s1c);
    __syncthreads();                       // K1 DMA drained; S(0) reads of buf0 done

    for (int t = 1; t < 64; ++t) {
        if (t + 1 < 64) prefetch_k(t + 1);       // -> buf (t+1)&1 (= buf read by S(t-1), done)

        s0p = s0c; s1p = s1c;                     // retire S(t-1) results
        s_phase((const char*)&Klds[t & 1][0], s0c, s1c);   // S(t) in flight...
        softmax_store(s0p, s1p, (t - 1) & 1);     // ...while softmax(t-1) runs on VALU

        __syncthreads();   // P(t-1)/alpha visible; K(t+1) drained; buf[t&1] reads done

        pv_phase((t - 1) & 1, (t - 1) << 5);
    }

    // epilogue: tile 63
    softmax_store(s0c, s1c, 1);
    __syncthreads();
    pv_phase(1, 63 << 5);

    // final l for all 128 rows -> LDS
    if (hi == 0) lred[wv * 16 + lr] = lrun;
    __syncthreads();

    const int b = bh >> 3, h = bh & 7;
#pragma unroll
    for (int mf = 0; mf < 4; ++mf) {
        f32x4 lv = *(const f32x4*)&lred[qh * 64 + mf * 16 + hi * 4];
        f32x4 inv;
#pragma unroll
        for (int r = 0; r < 4; ++r) inv[r] = 1.0f / lv[r];
#pragma unroll
        for (int nf = 0; nf < 8; ++nf) {
            int d = ds * 128 + nf * 16 + lr;
#pragma unroll
            for (int r = 0; r < 4; ++r) {
                int t = q0 + qh * 64 + mf * 16 + hi * 4 + r;
                O[((size_t)(b * 2048 + t)) * 4096 + h * 512 + d] = f2bf(acc[mf][nf][r] * inv[r]);
            }
        }
    }
}

// ---------- host ----------
extern "C" void kernel_launch(void* const* d_in, const int* in_sizes, int n_in,
                              void* d_out, int out_size, void* d_ws, size_t ws_size,
                              hipStream_t stream) {
    const float* x  = (const float*)d_in[0];
    const float* Wq = (const float*)d_in[1];
    const float* Wk = (const float*)d_in[2];
    const float* Wv = (const float*)d_in[3];
    const float* Wu = (const float*)d_in[4];
    const float* bu = (const float*)d_in[5];

    char* ws = (char*)d_ws;
    const size_t MB = 1ull << 20;
    u16* xb  = (u16*)(ws + 0);          // 4 MB  x as bf16 [4096][512]
    u16* Wqt = (u16*)(ws + 4 * MB);     // 3 x 4 MB: Wq^T,Wk^T,Wv^T bf16 [4096][512] contiguous
    u16* Wut = (u16*)(ws + 16 * MB);    // 4 MB  Wu^T bf16 [512][4096]
    u16* Qb  = (u16*)(ws + 20 * MB);    // 2 x 32 MB: Q,K [bh][t][d] (Q pre-scaled)
    u16* Kb  = (u16*)(ws + 52 * MB);
    u16* Vtb = (u16*)(ws + 116 * MB);   // 32 MB [bh][d][t] (written directly by gemm_qkv z=2)
    u16* Ob  = (u16*)(ws + 84 * MB);    // 32 MB [b*t][h*d]

    prep_kernel<<<4096, 256, 0, stream>>>(x, Wq, Wk, Wv, Wu, xb, Wqt, Wut);

    // 512^-0.5 * log2(e): softmax runs in base-2 (exp2f), fold conversion into Q scale
    const float s2 = 0.06375871593f;
    gemm_qkv<<<dim3(32, 32, 3), 256, 0, stream>>>(xb, Wqt, s2, Qb, Vtb);

    attn_kernel<<<256, 512, 0, stream>>>(Qb, Kb, Vtb, Ob);

    gemm_final<<<dim3(16, 64), 256, 0, stream>>>(Ob, Wut, bu, (float*)d_out, 4096);
}